// Round 2
// baseline (379.653 us; speedup 1.0000x reference)
//
#include <hip/hip_runtime.h>
#include <hip/hip_bf16.h>

// Problem constants (fixed shapes)
constexpr int B = 16, S = 512, D = 512, H = 8, HD = 64;
constexpr int BS = B * S;   // 8192 rows

typedef __attribute__((ext_vector_type(8))) short bf16x8;
typedef __attribute__((ext_vector_type(4))) float f32x4;

#define DEVI __device__ __forceinline__

DEVI bf16x8 ldbf8(const __hip_bfloat16* p) {
    return *reinterpret_cast<const bf16x8*>(p);
}

DEVI unsigned short bfbits(float f) {
    __hip_bfloat16 h = __float2bfloat16(f);
    return __builtin_bit_cast(unsigned short, h);
}

// ---------------- fp32 -> bf16 conversion (vectorized) ----------------
__global__ __launch_bounds__(256) void cvt_kernel(const float* __restrict__ src,
                                                  __hip_bfloat16* __restrict__ dst,
                                                  int n4) {
    int i = blockIdx.x * 256 + threadIdx.x;
    if (i >= n4) return;
    float4 v = reinterpret_cast<const float4*>(src)[i];
    unsigned short a = bfbits(v.x), b = bfbits(v.y), c = bfbits(v.z), d = bfbits(v.w);
    unsigned int lo = (unsigned int)a | ((unsigned int)b << 16);
    unsigned int hi = (unsigned int)c | ((unsigned int)d << 16);
    uint2 o; o.x = lo; o.y = hi;
    reinterpret_cast<uint2*>(dst)[i] = o;
}

// ---------------- mem_attn: softmax over log10(ren+1)+exp(-|ts|), causal ----------------
// One wave per (b,q) row; 8 cols per lane. Output fp32 (B,S,S).
__global__ __launch_bounds__(256) void mem_attn_kernel(const float* __restrict__ ren,
                                                       const float* __restrict__ ts,
                                                       float* __restrict__ mem) {
    int tid = threadIdx.x;
    int w = tid >> 6, l = tid & 63;
    int row = blockIdx.x * 4 + w;        // b*S + q
    int qr = row & (S - 1);
    size_t base = (size_t)row * S + l * 8;
    float4 r0 = *reinterpret_cast<const float4*>(ren + base);
    float4 r1 = *reinterpret_cast<const float4*>(ren + base + 4);
    float4 t0 = *reinterpret_cast<const float4*>(ts + base);
    float4 t1 = *reinterpret_cast<const float4*>(ts + base + 4);
    float rv[8] = {r0.x, r0.y, r0.z, r0.w, r1.x, r1.y, r1.z, r1.w};
    float tv[8] = {t0.x, t0.y, t0.z, t0.w, t1.x, t1.y, t1.z, t1.w};
    float f[8];
    float m = -3.0e38f;
#pragma unroll
    for (int j = 0; j < 8; ++j) {
        int c = l * 8 + j;
        float v = (c <= qr) ? (__log2f(rv[j] + 1.0f) * 0.3010299957f + __expf(-fabsf(tv[j])))
                            : -3.0e38f;
        f[j] = v;
        m = fmaxf(m, v);
    }
#pragma unroll
    for (int off = 32; off >= 1; off >>= 1) m = fmaxf(m, __shfl_xor(m, off));
    float s = 0.f;
#pragma unroll
    for (int j = 0; j < 8; ++j) { float e = __expf(f[j] - m); f[j] = e; s += e; }
#pragma unroll
    for (int off = 32; off >= 1; off >>= 1) s += __shfl_xor(s, off);
    float inv = 1.0f / s;
    float4 o0 = make_float4(f[0] * inv, f[1] * inv, f[2] * inv, f[3] * inv);
    float4 o1 = make_float4(f[4] * inv, f[5] * inv, f[6] * inv, f[7] * inv);
    *reinterpret_cast<float4*>(mem + base) = o0;
    *reinterpret_cast<float4*>(mem + base + 4) = o1;
}

// ---------------- generic bf16 GEMM: C[i,j] = sum_d A[i,d]*W[j,d] + bias[j] ----------------
// M=8192, N=512, K=512. Block 256 thr = 4 waves (2x2), wave tile 64x64, block tile 128x128.
// MODE 0: store bf16 to (B,H,S,hd)  (q/k projection)
// MODE 1: store bf16 to (B,H,hd,S)  (v transposed)
// MODE 2: store fp32 + bf16 row-major (Wo)
// MODE 3: store fp32 row-major, += resid (W1 + residual)
template <int MODE>
__global__ __launch_bounds__(256) void gemm_bt(const __hip_bfloat16* __restrict__ A,
                                               const __hip_bfloat16* __restrict__ W,
                                               const float* __restrict__ bias,
                                               float* __restrict__ outf,
                                               __hip_bfloat16* __restrict__ outb,
                                               const float* __restrict__ resid) {
    constexpr int K = 512;
    int tid = threadIdx.x;
    int wv = tid >> 6, l = tid & 63;
    int wR = wv >> 1, wC = wv & 1;
    int lr = l & 15, lg = l >> 4;
    int rowBase = blockIdx.x * 128 + wR * 64;
    int colBase = blockIdx.y * 128 + wC * 64;
    const __hip_bfloat16* Ab = A + (size_t)(rowBase + lr) * K + lg * 8;
    const __hip_bfloat16* Wb = W + (size_t)(colBase + lr) * K + lg * 8;

    f32x4 acc[4][4];
#pragma unroll
    for (int m = 0; m < 4; ++m)
#pragma unroll
        for (int n = 0; n < 4; ++n) acc[m][n] = (f32x4){0.f, 0.f, 0.f, 0.f};

    for (int kk = 0; kk < K; kk += 32) {
        bf16x8 a[4], b[4];
#pragma unroll
        for (int m = 0; m < 4; ++m) a[m] = ldbf8(Ab + (size_t)m * 16 * K + kk);
#pragma unroll
        for (int n = 0; n < 4; ++n) b[n] = ldbf8(Wb + (size_t)n * 16 * K + kk);
#pragma unroll
        for (int m = 0; m < 4; ++m)
#pragma unroll
            for (int n = 0; n < 4; ++n)
                acc[m][n] = __builtin_amdgcn_mfma_f32_16x16x32_bf16(a[m], b[n], acc[m][n], 0, 0, 0);
    }

#pragma unroll
    for (int n = 0; n < 4; ++n) {
        int col = colBase + n * 16 + lr;
        float bs = bias[col];
#pragma unroll
        for (int m = 0; m < 4; ++m) {
#pragma unroll
            for (int i = 0; i < 4; ++i) {
                int row = rowBase + m * 16 + lg * 4 + i;
                float val = acc[m][n][i] + bs;
                if constexpr (MODE == 0) {
                    int b_ = row >> 9, s_ = row & 511, h_ = col >> 6, d_ = col & 63;
                    outb[(((size_t)(b_ * 8 + h_) * 512 + s_) << 6) + d_] = __float2bfloat16(val);
                } else if constexpr (MODE == 1) {
                    int b_ = row >> 9, s_ = row & 511, h_ = col >> 6, d_ = col & 63;
                    outb[(((size_t)(b_ * 8 + h_) * 64 + d_) << 9) + s_] = __float2bfloat16(val);
                } else if constexpr (MODE == 2) {
                    size_t idx = (size_t)row * 512 + col;
                    outf[idx] = val;
                    outb[idx] = __float2bfloat16(val);
                } else {
                    size_t idx = (size_t)row * 512 + col;
                    outf[idx] = val + resid[idx];
                }
            }
        }
    }
}

// ---------------- fused attention ----------------
// Block = (b,h,qtile of 64 rows); 4 waves, wave w owns rows [q0+16w, q0+16w+16).
// Scores kept in VGPR MFMA accumulators (16x512 per wave), causal tiles skipped
// (wave-uniform guards, fully unrolled -> static reg indexing). Softmax via
// 16-lane shfl_xor. p blended with mem_attn, stored bf16 in LDS, then PV MFMA
// against vT (B,H,hd,S). NEG masking reproduces exact-0 probabilities.
constexpr int PS = 520;  // LDS row stride in bf16 elems (padded: 1040B = 65*16B)

__global__ __launch_bounds__(256) void attn_kernel(const __hip_bfloat16* __restrict__ Q,
                                                   const __hip_bfloat16* __restrict__ Km,
                                                   const __hip_bfloat16* __restrict__ VT,
                                                   const float* __restrict__ mem,
                                                   const float* __restrict__ l1,
                                                   __hip_bfloat16* __restrict__ outb) {
    __shared__ __hip_bfloat16 p_lds[64 * PS];
    int tid = threadIdx.x;
    int w = tid >> 6, l = tid & 63;
    int lr = l & 15, lg = l >> 4;
    int blk = blockIdx.x;
    int qt = blk & 7, bh = blk >> 3, h = bh & 7, b = bh >> 3;
    int q0 = qt * 64;
    int myrow = q0 + w * 16 + lg * 4;   // +i
    int numKt = (q0 >> 4) + w + 1;      // k-tiles with any unmasked col for this wave

    const __hip_bfloat16* qp = Q + ((size_t)bh * 512 + q0 + w * 16 + lr) * 64 + lg * 8;
    bf16x8 qa0 = ldbf8(qp), qa1 = ldbf8(qp + 32);

    f32x4 acc[32];
    const __hip_bfloat16* kp = Km + ((size_t)bh * 512 + lr) * 64 + lg * 8;
#pragma unroll
    for (int kt = 0; kt < 32; ++kt) {
        if (kt < numKt) {
            bf16x8 k0 = ldbf8(kp + (size_t)kt * 16 * 64);
            bf16x8 k1 = ldbf8(kp + (size_t)kt * 16 * 64 + 32);
            f32x4 c = {0.f, 0.f, 0.f, 0.f};
            c = __builtin_amdgcn_mfma_f32_16x16x32_bf16(qa0, k0, c, 0, 0, 0);
            c = __builtin_amdgcn_mfma_f32_16x16x32_bf16(qa1, k1, c, 0, 0, 0);
            acc[kt] = c;
        }
    }

    // mask + scale, row max
    float rmax[4] = {-3e38f, -3e38f, -3e38f, -3e38f};
#pragma unroll
    for (int kt = 0; kt < 32; ++kt) {
        if (kt < numKt) {
            int colb = kt * 16 + lr;
#pragma unroll
            for (int i = 0; i < 4; ++i) {
                float v = (colb <= myrow + i) ? acc[kt][i] * 0.125f : -3e38f;
                acc[kt][i] = v;
                rmax[i] = fmaxf(rmax[i], v);
            }
        }
    }
#pragma unroll
    for (int off = 1; off < 16; off <<= 1) {
#pragma unroll
        for (int i = 0; i < 4; ++i) rmax[i] = fmaxf(rmax[i], __shfl_xor(rmax[i], off));
    }
    // exp + row sum
    float rsum[4] = {0.f, 0.f, 0.f, 0.f};
#pragma unroll
    for (int kt = 0; kt < 32; ++kt) {
        if (kt < numKt) {
#pragma unroll
            for (int i = 0; i < 4; ++i) {
                float e = __expf(acc[kt][i] - rmax[i]);
                acc[kt][i] = e;
                rsum[i] += e;
            }
        }
    }
#pragma unroll
    for (int off = 1; off < 16; off <<= 1) {
#pragma unroll
        for (int i = 0; i < 4; ++i) rsum[i] += __shfl_xor(rsum[i], off);
    }

    float lam = l1[0];
    float rinv[4];
#pragma unroll
    for (int i = 0; i < 4; ++i) rinv[i] = (1.0f - lam) / rsum[i];

    // blend with mem_attn, write p (bf16) to LDS
    const float* memp = mem + ((size_t)b * 512 + myrow) * 512;
#pragma unroll
    for (int kt = 0; kt < 32; ++kt) {
        if (kt < numKt) {
            int colb = kt * 16 + lr;
#pragma unroll
            for (int i = 0; i < 4; ++i) {
                float p = acc[kt][i] * rinv[i] + lam * memp[(size_t)i * 512 + colb];
                p_lds[(w * 16 + lg * 4 + i) * PS + colb] = __float2bfloat16(p);
            }
        }
    }
    // zero the strip [numKt*16, q0+64) so the PV contraction reads zeros
    int ktEnd = (q0 >> 4) + 4;
    for (int kt = numKt; kt < ktEnd; ++kt) {
        int colb = kt * 16 + lr;
#pragma unroll
        for (int i = 0; i < 4; ++i)
            p_lds[(w * 16 + lg * 4 + i) * PS + colb] = __float2bfloat16(0.f);
    }
    __syncthreads();

    // PV: out(16x64 per wave) = p(16x512) @ v(512x64), contraction only over k < q0+64
    f32x4 acc2[4];
#pragma unroll
    for (int n = 0; n < 4; ++n) acc2[n] = (f32x4){0.f, 0.f, 0.f, 0.f};
    int ksteps = (q0 >> 5) + 2;
    const __hip_bfloat16* vp = VT + ((size_t)bh * 64 + lr) * 512 + lg * 8;
#pragma unroll
    for (int ks = 0; ks < 16; ++ks) {
        if (ks < ksteps) {
            bf16x8 pa = *reinterpret_cast<const bf16x8*>(&p_lds[(w * 16 + lr) * PS + ks * 32 + lg * 8]);
#pragma unroll
            for (int n = 0; n < 4; ++n) {
                bf16x8 vb = ldbf8(vp + (size_t)n * 16 * 512 + ks * 32);
                acc2[n] = __builtin_amdgcn_mfma_f32_16x16x32_bf16(pa, vb, acc2[n], 0, 0, 0);
            }
        }
    }

    __hip_bfloat16* op = outb + ((size_t)b * 512 + q0 + w * 16 + lg * 4) * 512 + h * 64;
#pragma unroll
    for (int n = 0; n < 4; ++n)
#pragma unroll
        for (int i = 0; i < 4; ++i)
            op[(size_t)i * 512 + n * 16 + lr] = __float2bfloat16(acc2[n][i]);
}

// ---------------- LayerNorm (in-place on d_out) ----------------
__global__ __launch_bounds__(256) void ln_kernel(float* __restrict__ io,
                                                 const float* __restrict__ g,
                                                 const float* __restrict__ bb) {
    int tid = threadIdx.x;
    int w = tid >> 6, l = tid & 63;
    size_t row = (size_t)blockIdx.x * 4 + w;
    float* p = io + row * 512 + l * 8;
    float4 x0 = *reinterpret_cast<float4*>(p);
    float4 x1 = *reinterpret_cast<float4*>(p + 4);
    float xs[8] = {x0.x, x0.y, x0.z, x0.w, x1.x, x1.y, x1.z, x1.w};
    float s = 0.f;
#pragma unroll
    for (int j = 0; j < 8; ++j) s += xs[j];
#pragma unroll
    for (int off = 32; off >= 1; off >>= 1) s += __shfl_xor(s, off);
    float mu = s * (1.0f / 512.0f);
    float vs = 0.f;
#pragma unroll
    for (int j = 0; j < 8; ++j) { float d = xs[j] - mu; vs += d * d; }
#pragma unroll
    for (int off = 32; off >= 1; off >>= 1) vs += __shfl_xor(vs, off);
    float rstd = rsqrtf(vs * (1.0f / 512.0f) + 1e-5f);
    const float4 g0 = *reinterpret_cast<const float4*>(g + l * 8);
    const float4 g1 = *reinterpret_cast<const float4*>(g + l * 8 + 4);
    const float4 b0 = *reinterpret_cast<const float4*>(bb + l * 8);
    const float4 b1 = *reinterpret_cast<const float4*>(bb + l * 8 + 4);
    float gs[8] = {g0.x, g0.y, g0.z, g0.w, g1.x, g1.y, g1.z, g1.w};
    float bs[8] = {b0.x, b0.y, b0.z, b0.w, b1.x, b1.y, b1.z, b1.w};
    float ys[8];
#pragma unroll
    for (int j = 0; j < 8; ++j) ys[j] = (xs[j] - mu) * rstd * gs[j] + bs[j];
    float4 y0 = make_float4(ys[0], ys[1], ys[2], ys[3]);
    float4 y1 = make_float4(ys[4], ys[5], ys[6], ys[7]);
    *reinterpret_cast<float4*>(p) = y0;
    *reinterpret_cast<float4*>(p + 4) = y1;
}

// ---------------- host ----------------
extern "C" void kernel_launch(void* const* d_in, const int* in_sizes, int n_in,
                              void* d_out, int out_size, void* d_ws, size_t ws_size,
                              hipStream_t stream) {
    // input order: query(0) inputs(1) ren_mat(2) timestamp(3) mask(4) Wq(5) bq(6)
    //              Wk(7) bk(8) Wv(9) bv(10) Wo(11) bo(12) W1(13) b1(14)
    //              ln_g(15) ln_b(16) l1(17) gammas(18)
    const float* inputs = (const float*)d_in[1];
    const float* ren    = (const float*)d_in[2];
    const float* ts     = (const float*)d_in[3];
    const float* Wq = (const float*)d_in[5];
    const float* bq = (const float*)d_in[6];
    const float* Wk = (const float*)d_in[7];
    const float* bk = (const float*)d_in[8];
    const float* Wv = (const float*)d_in[9];
    const float* bv = (const float*)d_in[10];
    const float* Wo = (const float*)d_in[11];
    const float* bo = (const float*)d_in[12];
    const float* W1 = (const float*)d_in[13];
    const float* b1 = (const float*)d_in[14];
    const float* ln_g = (const float*)d_in[15];
    const float* ln_b = (const float*)d_in[16];
    const float* l1   = (const float*)d_in[17];
    float* out = (float*)d_out;

    char* ws = (char*)d_ws;
    __hip_bfloat16* in_bf = (__hip_bfloat16*)(ws + 0);                 //  8,388,608
    __hip_bfloat16* wq_bf = (__hip_bfloat16*)(ws + 8388608);           //    524,288
    __hip_bfloat16* wk_bf = (__hip_bfloat16*)(ws + 8912896);
    __hip_bfloat16* wv_bf = (__hip_bfloat16*)(ws + 9437184);
    __hip_bfloat16* wo_bf = (__hip_bfloat16*)(ws + 9961472);
    __hip_bfloat16* w1_bf = (__hip_bfloat16*)(ws + 10485760);
    __hip_bfloat16* q_bf  = (__hip_bfloat16*)(ws + 11010048);          //  8,388,608
    __hip_bfloat16* k_bf  = (__hip_bfloat16*)(ws + 19398656);
    __hip_bfloat16* vT_bf = (__hip_bfloat16*)(ws + 27787264);
    float*          mem_f = (float*)(ws + 36175872);                   // 16,777,216
    __hip_bfloat16* ao_bf = (__hip_bfloat16*)(ws + 52953088);          //  8,388,608
    float*         out1_f = (float*)(ws + 61341696);                   // 16,777,216
    __hip_bfloat16* o1_bf = (__hip_bfloat16*)(ws + 78118912);          //  8,388,608
    // total ws use: 86,507,520 bytes

    // 1) convert inputs + weights to bf16
    cvt_kernel<<<4096, 256, 0, stream>>>(inputs, in_bf, BS * D / 4);
    cvt_kernel<<<256, 256, 0, stream>>>(Wq, wq_bf, D * D / 4);
    cvt_kernel<<<256, 256, 0, stream>>>(Wk, wk_bf, D * D / 4);
    cvt_kernel<<<256, 256, 0, stream>>>(Wv, wv_bf, D * D / 4);
    cvt_kernel<<<256, 256, 0, stream>>>(Wo, wo_bf, D * D / 4);
    cvt_kernel<<<256, 256, 0, stream>>>(W1, w1_bf, D * D / 4);

    // 2) projections
    dim3 ggrid(BS / 128, D / 128);
    gemm_bt<0><<<ggrid, 256, 0, stream>>>(in_bf, wq_bf, bq, nullptr, q_bf, nullptr);
    gemm_bt<0><<<ggrid, 256, 0, stream>>>(in_bf, wk_bf, bk, nullptr, k_bf, nullptr);
    gemm_bt<1><<<ggrid, 256, 0, stream>>>(in_bf, wv_bf, bv, nullptr, vT_bf, nullptr);

    // 3) memory attention (head-independent)
    mem_attn_kernel<<<BS / 4, 256, 0, stream>>>(ren, ts, mem_f);

    // 4) fused attention
    attn_kernel<<<B * H * (S / 64), 256, 0, stream>>>(q_bf, k_bf, vT_bf, mem_f, l1, ao_bf);

    // 5) output projection (fp32 + bf16 copies)
    gemm_bt<2><<<ggrid, 256, 0, stream>>>(ao_bf, wo_bf, bo, out1_f, o1_bf, nullptr);

    // 6) FFN + residual -> d_out (fp32)
    gemm_bt<3><<<ggrid, 256, 0, stream>>>(o1_bf, w1_bf, b1, out, nullptr, out1_f);

    // 7) LayerNorm in-place on d_out
    ln_kernel<<<BS / 4, 256, 0, stream>>>(out, ln_g, ln_b);
}

// Round 3
// 374.213 us; speedup vs baseline: 1.0145x; 1.0145x over previous
//
#include <hip/hip_runtime.h>
#include <hip/hip_bf16.h>

// Problem constants (fixed shapes)
constexpr int B = 16, S = 512, D = 512, H = 8, HD = 64;
constexpr int BS = B * S;   // 8192 rows

typedef __attribute__((ext_vector_type(8))) short bf16x8;
typedef __attribute__((ext_vector_type(4))) float f32x4;

#define DEVI __device__ __forceinline__

DEVI bf16x8 ldbf8(const __hip_bfloat16* p) {
    return *reinterpret_cast<const bf16x8*>(p);
}

DEVI unsigned short bfbits(float f) {
    __hip_bfloat16 h = __float2bfloat16(f);
    return __builtin_bit_cast(unsigned short, h);
}

// ---------------- fp32 -> bf16 conversion (vectorized) ----------------
__global__ __launch_bounds__(256) void cvt_kernel(const float* __restrict__ src,
                                                  __hip_bfloat16* __restrict__ dst,
                                                  int n4) {
    int i = blockIdx.x * 256 + threadIdx.x;
    if (i >= n4) return;
    float4 v = reinterpret_cast<const float4*>(src)[i];
    unsigned short a = bfbits(v.x), b = bfbits(v.y), c = bfbits(v.z), d = bfbits(v.w);
    unsigned int lo = (unsigned int)a | ((unsigned int)b << 16);
    unsigned int hi = (unsigned int)c | ((unsigned int)d << 16);
    uint2 o; o.x = lo; o.y = hi;
    reinterpret_cast<uint2*>(dst)[i] = o;
}

// All 5 weight matrices (contiguous dst region) in one launch.
__global__ __launch_bounds__(256) void wcvt_kernel(const float* __restrict__ s0,
                                                   const float* __restrict__ s1,
                                                   const float* __restrict__ s2,
                                                   const float* __restrict__ s3,
                                                   const float* __restrict__ s4,
                                                   __hip_bfloat16* __restrict__ dst) {
    int idx = blockIdx.x * 256 + threadIdx.x;      // [0, 5*65536)
    int wsel = idx >> 16;                          // uniform per block
    int off = idx & 65535;
    const float* s;
    switch (wsel) {
        case 0: s = s0; break;
        case 1: s = s1; break;
        case 2: s = s2; break;
        case 3: s = s3; break;
        default: s = s4; break;
    }
    float4 v = reinterpret_cast<const float4*>(s)[off];
    unsigned int lo = (unsigned int)bfbits(v.x) | ((unsigned int)bfbits(v.y) << 16);
    unsigned int hi = (unsigned int)bfbits(v.z) | ((unsigned int)bfbits(v.w) << 16);
    uint2 o; o.x = lo; o.y = hi;
    reinterpret_cast<uint2*>(dst)[idx] = o;
}

// ---------------- mem_attn: softmax over log10(ren+1)+exp(-|ts|), causal ----------------
// One wave per (b,q) row; 8 cols per lane. Output bf16 (B,S,S); masked cols exact 0.
// Loads skipped for fully-masked 8-col chunks (halves fp32 read traffic).
__global__ __launch_bounds__(256) void mem_attn_kernel(const float* __restrict__ ren,
                                                       const float* __restrict__ ts,
                                                       __hip_bfloat16* __restrict__ mem) {
    int tid = threadIdx.x;
    int w = tid >> 6, l = tid & 63;
    int row = blockIdx.x * 4 + w;        // b*S + q
    int qr = row & (S - 1);
    size_t base = (size_t)row * S + l * 8;
    float f[8];
    bool active = (l * 8 <= qr);
    if (active) {
        float4 r0 = *reinterpret_cast<const float4*>(ren + base);
        float4 r1 = *reinterpret_cast<const float4*>(ren + base + 4);
        float4 t0 = *reinterpret_cast<const float4*>(ts + base);
        float4 t1 = *reinterpret_cast<const float4*>(ts + base + 4);
        float rv[8] = {r0.x, r0.y, r0.z, r0.w, r1.x, r1.y, r1.z, r1.w};
        float tv[8] = {t0.x, t0.y, t0.z, t0.w, t1.x, t1.y, t1.z, t1.w};
#pragma unroll
        for (int j = 0; j < 8; ++j) {
            int c = l * 8 + j;
            f[j] = (c <= qr) ? (__log2f(rv[j] + 1.0f) * 0.3010299957f + __expf(-fabsf(tv[j])))
                             : -3.0e38f;
        }
    } else {
#pragma unroll
        for (int j = 0; j < 8; ++j) f[j] = -3.0e38f;
    }
    float m = -3.0e38f;
#pragma unroll
    for (int j = 0; j < 8; ++j) m = fmaxf(m, f[j]);
#pragma unroll
    for (int off = 32; off >= 1; off >>= 1) m = fmaxf(m, __shfl_xor(m, off));
    float s = 0.f;
#pragma unroll
    for (int j = 0; j < 8; ++j) { float e = __expf(f[j] - m); f[j] = e; s += e; }
#pragma unroll
    for (int off = 32; off >= 1; off >>= 1) s += __shfl_xor(s, off);
    float inv = 1.0f / s;
    bf16x8 o;
#pragma unroll
    for (int j = 0; j < 8; ++j) o[j] = (short)bfbits(f[j] * inv);
    *reinterpret_cast<bf16x8*>(mem + base) = o;
}

// ---------------- generic bf16 GEMM: C[i,j] = sum_d A[i,d]*W[j,d] + bias[j] ----------------
// MODE 0: store bf16 to (B,H,S,hd)  (q/k projection)
// MODE 1: store bf16 to (B,H,hd,S)  (v transposed)
// MODE 2: store fp32 + bf16 row-major (Wo)
// MODE 3: store fp32 row-major, += resid (W1 + residual)
template <int MODE>
__global__ __launch_bounds__(256) void gemm_bt(const __hip_bfloat16* __restrict__ A,
                                               const __hip_bfloat16* __restrict__ W,
                                               const float* __restrict__ bias,
                                               float* __restrict__ outf,
                                               __hip_bfloat16* __restrict__ outb,
                                               const float* __restrict__ resid) {
    constexpr int K = 512;
    int tid = threadIdx.x;
    int wv = tid >> 6, l = tid & 63;
    int wR = wv >> 1, wC = wv & 1;
    int lr = l & 15, lg = l >> 4;
    int rowBase = blockIdx.x * 128 + wR * 64;
    int colBase = blockIdx.y * 128 + wC * 64;
    const __hip_bfloat16* Ab = A + (size_t)(rowBase + lr) * K + lg * 8;
    const __hip_bfloat16* Wb = W + (size_t)(colBase + lr) * K + lg * 8;

    f32x4 acc[4][4];
#pragma unroll
    for (int m = 0; m < 4; ++m)
#pragma unroll
        for (int n = 0; n < 4; ++n) acc[m][n] = (f32x4){0.f, 0.f, 0.f, 0.f};

    for (int kk = 0; kk < K; kk += 32) {
        bf16x8 a[4], b[4];
#pragma unroll
        for (int m = 0; m < 4; ++m) a[m] = ldbf8(Ab + (size_t)m * 16 * K + kk);
#pragma unroll
        for (int n = 0; n < 4; ++n) b[n] = ldbf8(Wb + (size_t)n * 16 * K + kk);
#pragma unroll
        for (int m = 0; m < 4; ++m)
#pragma unroll
            for (int n = 0; n < 4; ++n)
                acc[m][n] = __builtin_amdgcn_mfma_f32_16x16x32_bf16(a[m], b[n], acc[m][n], 0, 0, 0);
    }

#pragma unroll
    for (int n = 0; n < 4; ++n) {
        int col = colBase + n * 16 + lr;
        float bs = bias[col];
#pragma unroll
        for (int m = 0; m < 4; ++m) {
#pragma unroll
            for (int i = 0; i < 4; ++i) {
                int row = rowBase + m * 16 + lg * 4 + i;
                float val = acc[m][n][i] + bs;
                if constexpr (MODE == 0) {
                    int b_ = row >> 9, s_ = row & 511, h_ = col >> 6, d_ = col & 63;
                    outb[(((size_t)(b_ * 8 + h_) * 512 + s_) << 6) + d_] = __float2bfloat16(val);
                } else if constexpr (MODE == 1) {
                    int b_ = row >> 9, s_ = row & 511, h_ = col >> 6, d_ = col & 63;
                    outb[(((size_t)(b_ * 8 + h_) * 64 + d_) << 9) + s_] = __float2bfloat16(val);
                } else if constexpr (MODE == 2) {
                    size_t idx = (size_t)row * 512 + col;
                    outf[idx] = val;
                    outb[idx] = __float2bfloat16(val);
                } else {
                    size_t idx = (size_t)row * 512 + col;
                    outf[idx] = val + resid[idx];
                }
            }
        }
    }
}

// ---------------- memV GEMM: memv[b,q,h*64+d] = sum_k mem[b,q,k] * vT[b,h,d,k] ----------------
// mem's masked entries are exact zeros -> dense GEMM, but k>rowmax contributes 0,
// so clip the K loop per row-block (triangular skip, ~2x work saving).
__global__ __launch_bounds__(256) void gemm_memv(const __hip_bfloat16* __restrict__ A,
                                                 const __hip_bfloat16* __restrict__ VT,
                                                 __hip_bfloat16* __restrict__ outb) {
    int tid = threadIdx.x;
    int wv = tid >> 6, l = tid & 63;
    int wR = wv >> 1, wC = wv & 1;
    int lr = l & 15, lg = l >> 4;
    int rowBase = blockIdx.x * 128 + wR * 64;       // global row (b*512+q base)
    int colBase = blockIdx.y * 128 + wC * 64;       // 64-aligned -> single head per wave
    int b = rowBase >> 9;
    int h = colBase >> 6;
    int klim = ((blockIdx.x & 3) + 1) * 128;        // max k needed for this row-block

    const __hip_bfloat16* Ab = A + (size_t)(rowBase + lr) * 512 + lg * 8;
    const __hip_bfloat16* Wb = VT + ((size_t)(b * 8 + h) * 64 + lr) * 512 + lg * 8;

    f32x4 acc[4][4];
#pragma unroll
    for (int m = 0; m < 4; ++m)
#pragma unroll
        for (int n = 0; n < 4; ++n) acc[m][n] = (f32x4){0.f, 0.f, 0.f, 0.f};

    for (int kk = 0; kk < klim; kk += 32) {
        bf16x8 a[4], bb[4];
#pragma unroll
        for (int m = 0; m < 4; ++m) a[m] = ldbf8(Ab + (size_t)m * 16 * 512 + kk);
#pragma unroll
        for (int n = 0; n < 4; ++n) bb[n] = ldbf8(Wb + (size_t)n * 16 * 512 + kk);
#pragma unroll
        for (int m = 0; m < 4; ++m)
#pragma unroll
            for (int n = 0; n < 4; ++n)
                acc[m][n] = __builtin_amdgcn_mfma_f32_16x16x32_bf16(a[m], bb[n], acc[m][n], 0, 0, 0);
    }

#pragma unroll
    for (int n = 0; n < 4; ++n) {
        int col = colBase + n * 16 + lr;
#pragma unroll
        for (int m = 0; m < 4; ++m)
#pragma unroll
            for (int i = 0; i < 4; ++i) {
                int row = rowBase + m * 16 + lg * 4 + i;
                outb[(size_t)row * 512 + col] = __float2bfloat16(acc[m][n][i]);
            }
    }
}

// ---------------- fused attention ----------------
// Block = (b,h,qtile of 64 rows); 4 waves, wave w owns rows [q0+16w, q0+16w+16).
// Scores in VGPR accumulators; causal tiles skipped (wave-uniform guards, unrolled).
// P transposed for PV via per-wave chunked LDS (4KB x dbuf x 4 waves = 32KB, no
// __syncthreads -- wave-local) with XOR swizzle (row&7)<<3 for conflict-free b128 reads.
// out = (1-lam)*prob@V + lam*memV (memV precomputed by gemm_memv).
__global__ __launch_bounds__(256) void attn_kernel(const __hip_bfloat16* __restrict__ Q,
                                                   const __hip_bfloat16* __restrict__ Km,
                                                   const __hip_bfloat16* __restrict__ VT,
                                                   const __hip_bfloat16* __restrict__ memv,
                                                   const float* __restrict__ l1,
                                                   __hip_bfloat16* __restrict__ outb) {
    __shared__ short p_lds[16384];   // 4 waves x 2 buf x 2048 shorts (4KB each)
    int tid = threadIdx.x;
    int w = tid >> 6, l = tid & 63;
    int lr = l & 15, lg = l >> 4;
    int blk = blockIdx.x;
    int qt = blk & 7, bh = blk >> 3, h = bh & 7, b = bh >> 3;
    int q0 = qt * 64;
    int myrow = q0 + w * 16 + lg * 4;   // +i
    int numKt = (q0 >> 4) + w + 1;      // k-tiles with any unmasked col for this wave
    int ktEnd = (q0 >> 4) + 4;          // k-tiles covered by the block's PV contraction
    int ksteps = (q0 >> 5) + 2;         // 32-col MFMA steps in PV

    const __hip_bfloat16* qp = Q + ((size_t)bh * 512 + q0 + w * 16 + lr) * 64 + lg * 8;
    bf16x8 qa0 = ldbf8(qp), qa1 = ldbf8(qp + 32);

    f32x4 acc[32];
    const __hip_bfloat16* kp = Km + ((size_t)bh * 512 + lr) * 64 + lg * 8;
#pragma unroll
    for (int kt = 0; kt < 32; ++kt) {
        if (kt < numKt) {
            bf16x8 k0 = ldbf8(kp + (size_t)kt * 16 * 64);
            bf16x8 k1 = ldbf8(kp + (size_t)kt * 16 * 64 + 32);
            f32x4 c = {0.f, 0.f, 0.f, 0.f};
            c = __builtin_amdgcn_mfma_f32_16x16x32_bf16(qa0, k0, c, 0, 0, 0);
            c = __builtin_amdgcn_mfma_f32_16x16x32_bf16(qa1, k1, c, 0, 0, 0);
            acc[kt] = c;
        }
    }

    // mask + scale, row max
    float rmax[4] = {-3e38f, -3e38f, -3e38f, -3e38f};
#pragma unroll
    for (int kt = 0; kt < 32; ++kt) {
        if (kt < numKt) {
            int colb = kt * 16 + lr;
#pragma unroll
            for (int i = 0; i < 4; ++i) {
                float v = (colb <= myrow + i) ? acc[kt][i] * 0.125f : -3e38f;
                acc[kt][i] = v;
                rmax[i] = fmaxf(rmax[i], v);
            }
        }
    }
#pragma unroll
    for (int off = 1; off < 16; off <<= 1) {
#pragma unroll
        for (int i = 0; i < 4; ++i) rmax[i] = fmaxf(rmax[i], __shfl_xor(rmax[i], off));
    }
    // exp + row sum
    float rsum[4] = {0.f, 0.f, 0.f, 0.f};
#pragma unroll
    for (int kt = 0; kt < 32; ++kt) {
        if (kt < numKt) {
#pragma unroll
            for (int i = 0; i < 4; ++i) {
                float e = __expf(acc[kt][i] - rmax[i]);
                acc[kt][i] = e;
                rsum[i] += e;
            }
        }
    }
#pragma unroll
    for (int off = 1; off < 16; off <<= 1) {
#pragma unroll
        for (int i = 0; i < 4; ++i) rsum[i] += __shfl_xor(rsum[i], off);
    }

    float lam = l1[0];
    float rinv[4];
#pragma unroll
    for (int i = 0; i < 4; ++i) rinv[i] = (1.0f - lam) / rsum[i];

    // Chunked transpose-through-LDS + PV. Each chunk: 8 k-tiles (128 cols).
    f32x4 acc2[4];
#pragma unroll
    for (int n = 0; n < 4; ++n) acc2[n] = (f32x4){0.f, 0.f, 0.f, 0.f};
    const __hip_bfloat16* vp = VT + ((size_t)bh * 64 + lr) * 512 + lg * 8;

#pragma unroll
    for (int c = 0; c < 4; ++c) {
        int ktlo = c * 8;
        if (ktlo < ktEnd) {
            short* buf = &p_lds[(w * 2 + (c & 1)) * 2048];
            // write p (bf16, scaled by (1-lam)/rsum) with XOR swizzle
#pragma unroll
            for (int j = 0; j < 8; ++j) {
                int kt = ktlo + j;
                if (kt < numKt) {
#pragma unroll
                    for (int i = 0; i < 4; ++i) {
                        int r = lg * 4 + i;
                        buf[(r * 128 + j * 16 + lr) ^ ((r & 7) << 3)] =
                            (short)bfbits(acc[kt][i] * rinv[i]);
                    }
                } else if (kt < ktEnd) {
#pragma unroll
                    for (int i = 0; i < 4; ++i) {
                        int r = lg * 4 + i;
                        buf[(r * 128 + j * 16 + lr) ^ ((r & 7) << 3)] = 0;
                    }
                }
            }
            // PV over this chunk (wave-local; compiler inserts lgkmcnt waits)
#pragma unroll
            for (int sub = 0; sub < 4; ++sub) {
                int ks = c * 4 + sub;
                if (ks < ksteps) {
                    bf16x8 pa = *reinterpret_cast<bf16x8*>(
                        &buf[(lr * 128 + sub * 32 + lg * 8) ^ ((lr & 7) << 3)]);
#pragma unroll
                    for (int n = 0; n < 4; ++n) {
                        bf16x8 vb = ldbf8(vp + (size_t)n * 16 * 512 + ks * 32);
                        acc2[n] = __builtin_amdgcn_mfma_f32_16x16x32_bf16(pa, vb, acc2[n], 0, 0, 0);
                    }
                }
            }
        }
    }

    // epilogue: add lam * memV, store bf16
    const __hip_bfloat16* mvp = memv + ((size_t)b * 512 + q0 + w * 16 + lg * 4) * 512 + h * 64;
    __hip_bfloat16* op = outb + ((size_t)b * 512 + q0 + w * 16 + lg * 4) * 512 + h * 64;
#pragma unroll
    for (int n = 0; n < 4; ++n)
#pragma unroll
        for (int i = 0; i < 4; ++i) {
            float mv = __bfloat162float(mvp[(size_t)i * 512 + n * 16 + lr]);
            op[(size_t)i * 512 + n * 16 + lr] = __float2bfloat16(acc2[n][i] + lam * mv);
        }
}

// ---------------- LayerNorm (in-place on d_out) ----------------
__global__ __launch_bounds__(256) void ln_kernel(float* __restrict__ io,
                                                 const float* __restrict__ g,
                                                 const float* __restrict__ bb) {
    int tid = threadIdx.x;
    int w = tid >> 6, l = tid & 63;
    size_t row = (size_t)blockIdx.x * 4 + w;
    float* p = io + row * 512 + l * 8;
    float4 x0 = *reinterpret_cast<float4*>(p);
    float4 x1 = *reinterpret_cast<float4*>(p + 4);
    float xs[8] = {x0.x, x0.y, x0.z, x0.w, x1.x, x1.y, x1.z, x1.w};
    float s = 0.f;
#pragma unroll
    for (int j = 0; j < 8; ++j) s += xs[j];
#pragma unroll
    for (int off = 32; off >= 1; off >>= 1) s += __shfl_xor(s, off);
    float mu = s * (1.0f / 512.0f);
    float vs = 0.f;
#pragma unroll
    for (int j = 0; j < 8; ++j) { float d = xs[j] - mu; vs += d * d; }
#pragma unroll
    for (int off = 32; off >= 1; off >>= 1) vs += __shfl_xor(vs, off);
    float rstd = rsqrtf(vs * (1.0f / 512.0f) + 1e-5f);
    const float4 g0 = *reinterpret_cast<const float4*>(g + l * 8);
    const float4 g1 = *reinterpret_cast<const float4*>(g + l * 8 + 4);
    const float4 b0 = *reinterpret_cast<const float4*>(bb + l * 8);
    const float4 b1 = *reinterpret_cast<const float4*>(bb + l * 8 + 4);
    float gs[8] = {g0.x, g0.y, g0.z, g0.w, g1.x, g1.y, g1.z, g1.w};
    float bs[8] = {b0.x, b0.y, b0.z, b0.w, b1.x, b1.y, b1.z, b1.w};
    float ys[8];
#pragma unroll
    for (int j = 0; j < 8; ++j) ys[j] = (xs[j] - mu) * rstd * gs[j] + bs[j];
    float4 y0 = make_float4(ys[0], ys[1], ys[2], ys[3]);
    float4 y1 = make_float4(ys[4], ys[5], ys[6], ys[7]);
    *reinterpret_cast<float4*>(p) = y0;
    *reinterpret_cast<float4*>(p + 4) = y1;
}

// ---------------- host ----------------
extern "C" void kernel_launch(void* const* d_in, const int* in_sizes, int n_in,
                              void* d_out, int out_size, void* d_ws, size_t ws_size,
                              hipStream_t stream) {
    const float* inputs = (const float*)d_in[1];
    const float* ren    = (const float*)d_in[2];
    const float* ts     = (const float*)d_in[3];
    const float* Wq = (const float*)d_in[5];
    const float* bq = (const float*)d_in[6];
    const float* Wk = (const float*)d_in[7];
    const float* bk = (const float*)d_in[8];
    const float* Wv = (const float*)d_in[9];
    const float* bv = (const float*)d_in[10];
    const float* Wo = (const float*)d_in[11];
    const float* bo = (const float*)d_in[12];
    const float* W1 = (const float*)d_in[13];
    const float* b1 = (const float*)d_in[14];
    const float* ln_g = (const float*)d_in[15];
    const float* ln_b = (const float*)d_in[16];
    const float* l1   = (const float*)d_in[17];
    float* out = (float*)d_out;

    // ws layout (with lifetime-based reuse):
    //   [0, 8M)           in_bf        (dead after projections)  -> reused as ao_bf
    //   [8M, 10.5M)       5 weights bf16 (contiguous: wq wk wv wo w1)
    //   [10.5M+.5M=11010048, +8M)  q_bf   (dead after attn)      -> reused as o1_bf
    //   [19398656, +8M)   k_bf
    //   [27787264, +8M)   vT_bf
    //   [36175872, +33.5M) mem_bf      (dead after memv gemm)    -> first 16.7M reused as out1_f
    //   [69730304, +33.5M) memv_bf
    // total: 103,284,736 bytes
    char* ws = (char*)d_ws;
    __hip_bfloat16* in_bf = (__hip_bfloat16*)(ws + 0);
    __hip_bfloat16* ao_bf = (__hip_bfloat16*)(ws + 0);
    __hip_bfloat16* wq_bf = (__hip_bfloat16*)(ws + 8388608);
    __hip_bfloat16* wk_bf = (__hip_bfloat16*)(ws + 8912896);
    __hip_bfloat16* wv_bf = (__hip_bfloat16*)(ws + 9437184);
    __hip_bfloat16* wo_bf = (__hip_bfloat16*)(ws + 9961472);
    __hip_bfloat16* w1_bf = (__hip_bfloat16*)(ws + 10485760);
    __hip_bfloat16* q_bf  = (__hip_bfloat16*)(ws + 11010048);
    __hip_bfloat16* o1_bf = (__hip_bfloat16*)(ws + 11010048);
    __hip_bfloat16* k_bf  = (__hip_bfloat16*)(ws + 19398656);
    __hip_bfloat16* vT_bf = (__hip_bfloat16*)(ws + 27787264);
    __hip_bfloat16* mem_bf = (__hip_bfloat16*)(ws + 36175872);
    float*          out1_f = (float*)(ws + 36175872);
    __hip_bfloat16* memv_bf = (__hip_bfloat16*)(ws + 69730304);

    // 1) convert inputs + weights to bf16
    cvt_kernel<<<4096, 256, 0, stream>>>(inputs, in_bf, BS * D / 4);
    wcvt_kernel<<<1280, 256, 0, stream>>>(Wq, Wk, Wv, Wo, W1, wq_bf);

    // 2) projections
    dim3 ggrid(BS / 128, D / 128);
    gemm_bt<0><<<ggrid, 256, 0, stream>>>(in_bf, wq_bf, bq, nullptr, q_bf, nullptr);
    gemm_bt<0><<<ggrid, 256, 0, stream>>>(in_bf, wk_bf, bk, nullptr, k_bf, nullptr);
    gemm_bt<1><<<ggrid, 256, 0, stream>>>(in_bf, wv_bf, bv, nullptr, vT_bf, nullptr);

    // 3) memory attention (head-independent, bf16, exact zeros in masked region)
    mem_attn_kernel<<<BS / 4, 256, 0, stream>>>(ren, ts, mem_bf);

    // 4) memV = mem @ V  (dense batched GEMM w/ triangular K clip)
    gemm_memv<<<ggrid, 256, 0, stream>>>(mem_bf, vT_bf, memv_bf);

    // 5) fused attention: (1-lam)*softmax(QK^T)@V + lam*memV
    attn_kernel<<<B * H * (S / 64), 256, 0, stream>>>(q_bf, k_bf, vT_bf, memv_bf, l1, ao_bf);

    // 6) output projection (fp32 + bf16 copies)
    gemm_bt<2><<<ggrid, 256, 0, stream>>>(ao_bf, wo_bf, bo, out1_f, o1_bf, nullptr);

    // 7) FFN + residual -> d_out (fp32)
    gemm_bt<3><<<ggrid, 256, 0, stream>>>(o1_bf, w1_bf, b1, out, nullptr, out1_f);

    // 8) LayerNorm in-place on d_out
    ln_kernel<<<BS / 4, 256, 0, stream>>>(out, ln_g, ln_b);
}

// Round 7
// 287.876 us; speedup vs baseline: 1.3188x; 1.2999x over previous
//
#include <hip/hip_runtime.h>
#include <hip/hip_bf16.h>

// Problem constants (fixed shapes)
constexpr int B = 16, S = 512, D = 512, H = 8, HD = 64;
constexpr int BS = B * S;   // 8192 rows

typedef __attribute__((ext_vector_type(8))) short bf16x8;
typedef __attribute__((ext_vector_type(4))) float f32x4;

#define DEVI __device__ __forceinline__

DEVI bf16x8 ldbf8(const __hip_bfloat16* p) {
    return *reinterpret_cast<const bf16x8*>(p);
}

DEVI unsigned short bfbits(float f) {
    __hip_bfloat16 h = __float2bfloat16(f);
    return __builtin_bit_cast(unsigned short, h);
}

DEVI void gload_lds16(const void* g, void* l) {
    __builtin_amdgcn_global_load_lds((const __attribute__((address_space(1))) void*)g,
                                     (__attribute__((address_space(3))) void*)l, 16, 0, 0);
}

// ---------------- fp32 -> bf16 conversion (vectorized) ----------------
__global__ __launch_bounds__(256) void cvt_kernel(const float* __restrict__ src,
                                                  __hip_bfloat16* __restrict__ dst,
                                                  int n4) {
    int i = blockIdx.x * 256 + threadIdx.x;
    if (i >= n4) return;
    float4 v = reinterpret_cast<const float4*>(src)[i];
    unsigned int lo = (unsigned int)bfbits(v.x) | ((unsigned int)bfbits(v.y) << 16);
    unsigned int hi = (unsigned int)bfbits(v.z) | ((unsigned int)bfbits(v.w) << 16);
    uint2 o; o.x = lo; o.y = hi;
    reinterpret_cast<uint2*>(dst)[i] = o;
}

// All 5 weight matrices (contiguous dst region) in one launch.
__global__ __launch_bounds__(256) void wcvt_kernel(const float* __restrict__ s0,
                                                   const float* __restrict__ s1,
                                                   const float* __restrict__ s2,
                                                   const float* __restrict__ s3,
                                                   const float* __restrict__ s4,
                                                   __hip_bfloat16* __restrict__ dst) {
    int idx = blockIdx.x * 256 + threadIdx.x;      // [0, 5*65536)
    int wsel = idx >> 16;                          // uniform per block
    int off = idx & 65535;
    const float* s;
    switch (wsel) {
        case 0: s = s0; break;
        case 1: s = s1; break;
        case 2: s = s2; break;
        case 3: s = s3; break;
        default: s = s4; break;
    }
    float4 v = reinterpret_cast<const float4*>(s)[off];
    unsigned int lo = (unsigned int)bfbits(v.x) | ((unsigned int)bfbits(v.y) << 16);
    unsigned int hi = (unsigned int)bfbits(v.z) | ((unsigned int)bfbits(v.w) << 16);
    uint2 o; o.x = lo; o.y = hi;
    reinterpret_cast<uint2*>(dst)[idx] = o;
}

// ---------------- mem_attn: softmax over log10(ren+1)+exp(-|ts|), causal ----------------
__global__ __launch_bounds__(256) void mem_attn_kernel(const float* __restrict__ ren,
                                                       const float* __restrict__ ts,
                                                       __hip_bfloat16* __restrict__ mem) {
    int tid = threadIdx.x;
    int w = tid >> 6, l = tid & 63;
    int row = blockIdx.x * 4 + w;        // b*S + q
    int qr = row & (S - 1);
    size_t base = (size_t)row * S + l * 8;
    float f[8];
    bool active = (l * 8 <= qr);
    if (active) {
        float4 r0 = *reinterpret_cast<const float4*>(ren + base);
        float4 r1 = *reinterpret_cast<const float4*>(ren + base + 4);
        float4 t0 = *reinterpret_cast<const float4*>(ts + base);
        float4 t1 = *reinterpret_cast<const float4*>(ts + base + 4);
        float rv[8] = {r0.x, r0.y, r0.z, r0.w, r1.x, r1.y, r1.z, r1.w};
        float tv[8] = {t0.x, t0.y, t0.z, t0.w, t1.x, t1.y, t1.z, t1.w};
#pragma unroll
        for (int j = 0; j < 8; ++j) {
            int c = l * 8 + j;
            f[j] = (c <= qr) ? (__log2f(rv[j] + 1.0f) * 0.3010299957f + __expf(-fabsf(tv[j])))
                             : -3.0e38f;
        }
    } else {
#pragma unroll
        for (int j = 0; j < 8; ++j) f[j] = -3.0e38f;
    }
    float m = -3.0e38f;
#pragma unroll
    for (int j = 0; j < 8; ++j) m = fmaxf(m, f[j]);
#pragma unroll
    for (int off = 32; off >= 1; off >>= 1) m = fmaxf(m, __shfl_xor(m, off));
    float s = 0.f;
#pragma unroll
    for (int j = 0; j < 8; ++j) { float e = __expf(f[j] - m); f[j] = e; s += e; }
#pragma unroll
    for (int off = 32; off >= 1; off >>= 1) s += __shfl_xor(s, off);
    float inv = 1.0f / s;
    bf16x8 o;
#pragma unroll
    for (int j = 0; j < 8; ++j) o[j] = (short)bfbits(f[j] * inv);
    *reinterpret_cast<bf16x8*>(mem + base) = o;
}

// ---------------- merged q/k/v projection GEMM ----------------
// grid (64, 12): y -> mat = y>>2 (0=q,1=k,2=v), col block = (y&3)*128.
// Weights contiguous: Wqkv = [Wq|Wk|Wv], each D*D.
__global__ __launch_bounds__(256) void gemm_qkv(const __hip_bfloat16* __restrict__ A,
                                                const __hip_bfloat16* __restrict__ Wqkv,
                                                const float* __restrict__ bq,
                                                const float* __restrict__ bk,
                                                const float* __restrict__ bv,
                                                __hip_bfloat16* __restrict__ q_out,
                                                __hip_bfloat16* __restrict__ k_out,
                                                __hip_bfloat16* __restrict__ vT_out) {
    constexpr int K = 512;
    int tid = threadIdx.x;
    int wv = tid >> 6, l = tid & 63;
    int wR = wv >> 1, wC = wv & 1;
    int lr = l & 15, lg = l >> 4;
    int mat = blockIdx.y >> 2;
    int rowBase = blockIdx.x * 128 + wR * 64;
    int colBase = (blockIdx.y & 3) * 128 + wC * 64;
    const float* bias = (mat == 0) ? bq : (mat == 1) ? bk : bv;
    const __hip_bfloat16* W = Wqkv + (size_t)mat * D * D;
    const __hip_bfloat16* Ab = A + (size_t)(rowBase + lr) * K + lg * 8;
    const __hip_bfloat16* Wb = W + (size_t)(colBase + lr) * K + lg * 8;

    f32x4 acc[4][4];
#pragma unroll
    for (int m = 0; m < 4; ++m)
#pragma unroll
        for (int n = 0; n < 4; ++n) acc[m][n] = (f32x4){0.f, 0.f, 0.f, 0.f};

    for (int kk = 0; kk < K; kk += 32) {
        bf16x8 a[4], b[4];
#pragma unroll
        for (int m = 0; m < 4; ++m) a[m] = ldbf8(Ab + (size_t)m * 16 * K + kk);
#pragma unroll
        for (int n = 0; n < 4; ++n) b[n] = ldbf8(Wb + (size_t)n * 16 * K + kk);
#pragma unroll
        for (int m = 0; m < 4; ++m)
#pragma unroll
            for (int n = 0; n < 4; ++n)
                acc[m][n] = __builtin_amdgcn_mfma_f32_16x16x32_bf16(a[m], b[n], acc[m][n], 0, 0, 0);
    }

#pragma unroll
    for (int n = 0; n < 4; ++n) {
        int col = colBase + n * 16 + lr;
        float bs = bias[col];
#pragma unroll
        for (int m = 0; m < 4; ++m) {
#pragma unroll
            for (int i = 0; i < 4; ++i) {
                int row = rowBase + m * 16 + lg * 4 + i;
                float val = acc[m][n][i] + bs;
                int b_ = row >> 9, s_ = row & 511, h_ = col >> 6, d_ = col & 63;
                if (mat == 2) {
                    vT_out[(((size_t)(b_ * 8 + h_) * 64 + d_) << 9) + s_] = __float2bfloat16(val);
                } else {
                    __hip_bfloat16* o = (mat == 0) ? q_out : k_out;
                    o[(((size_t)(b_ * 8 + h_) * 512 + s_) << 6) + d_] = __float2bfloat16(val);
                }
            }
        }
    }
}

// ---------------- generic bf16 GEMM (Wo / W1 epilogues) ----------------
// MODE 2: store fp32 + bf16 row-major (Wo)
// MODE 3: store fp32 row-major, += resid (W1 + residual)
template <int MODE>
__global__ __launch_bounds__(256) void gemm_bt(const __hip_bfloat16* __restrict__ A,
                                               const __hip_bfloat16* __restrict__ W,
                                               const float* __restrict__ bias,
                                               float* __restrict__ outf,
                                               __hip_bfloat16* __restrict__ outb,
                                               const float* __restrict__ resid) {
    constexpr int K = 512;
    int tid = threadIdx.x;
    int wv = tid >> 6, l = tid & 63;
    int wR = wv >> 1, wC = wv & 1;
    int lr = l & 15, lg = l >> 4;
    int rowBase = blockIdx.x * 128 + wR * 64;
    int colBase = blockIdx.y * 128 + wC * 64;
    const __hip_bfloat16* Ab = A + (size_t)(rowBase + lr) * K + lg * 8;
    const __hip_bfloat16* Wb = W + (size_t)(colBase + lr) * K + lg * 8;

    f32x4 acc[4][4];
#pragma unroll
    for (int m = 0; m < 4; ++m)
#pragma unroll
        for (int n = 0; n < 4; ++n) acc[m][n] = (f32x4){0.f, 0.f, 0.f, 0.f};

    for (int kk = 0; kk < K; kk += 32) {
        bf16x8 a[4], b[4];
#pragma unroll
        for (int m = 0; m < 4; ++m) a[m] = ldbf8(Ab + (size_t)m * 16 * K + kk);
#pragma unroll
        for (int n = 0; n < 4; ++n) b[n] = ldbf8(Wb + (size_t)n * 16 * K + kk);
#pragma unroll
        for (int m = 0; m < 4; ++m)
#pragma unroll
            for (int n = 0; n < 4; ++n)
                acc[m][n] = __builtin_amdgcn_mfma_f32_16x16x32_bf16(a[m], b[n], acc[m][n], 0, 0, 0);
    }

#pragma unroll
    for (int n = 0; n < 4; ++n) {
        int col = colBase + n * 16 + lr;
        float bs = bias[col];
#pragma unroll
        for (int m = 0; m < 4; ++m) {
#pragma unroll
            for (int i = 0; i < 4; ++i) {
                int row = rowBase + m * 16 + lg * 4 + i;
                float val = acc[m][n][i] + bs;
                size_t idx = (size_t)row * 512 + col;
                if constexpr (MODE == 2) {
                    outf[idx] = val;
                    outb[idx] = __float2bfloat16(val);
                } else {
                    outf[idx] = val + resid[idx];
                }
            }
        }
    }
}

// ---------------- memV GEMM: memv[b,q,h*64+d] = sum_k mem[b,q,k] * vT[b,h,d,k] ----------------
__global__ __launch_bounds__(256) void gemm_memv(const __hip_bfloat16* __restrict__ A,
                                                 const __hip_bfloat16* __restrict__ VT,
                                                 __hip_bfloat16* __restrict__ outb) {
    int tid = threadIdx.x;
    int wv = tid >> 6, l = tid & 63;
    int wR = wv >> 1, wC = wv & 1;
    int lr = l & 15, lg = l >> 4;
    int rowBase = blockIdx.x * 128 + wR * 64;
    int colBase = blockIdx.y * 128 + wC * 64;
    int b = rowBase >> 9;
    int h = colBase >> 6;
    int klim = ((blockIdx.x & 3) + 1) * 128;

    const __hip_bfloat16* Ab = A + (size_t)(rowBase + lr) * 512 + lg * 8;
    const __hip_bfloat16* Wb = VT + ((size_t)(b * 8 + h) * 64 + lr) * 512 + lg * 8;

    f32x4 acc[4][4];
#pragma unroll
    for (int m = 0; m < 4; ++m)
#pragma unroll
        for (int n = 0; n < 4; ++n) acc[m][n] = (f32x4){0.f, 0.f, 0.f, 0.f};

    for (int kk = 0; kk < klim; kk += 32) {
        bf16x8 a[4], bb[4];
#pragma unroll
        for (int m = 0; m < 4; ++m) a[m] = ldbf8(Ab + (size_t)m * 16 * 512 + kk);
#pragma unroll
        for (int n = 0; n < 4; ++n) bb[n] = ldbf8(Wb + (size_t)n * 16 * 512 + kk);
#pragma unroll
        for (int m = 0; m < 4; ++m)
#pragma unroll
            for (int n = 0; n < 4; ++n)
                acc[m][n] = __builtin_amdgcn_mfma_f32_16x16x32_bf16(a[m], bb[n], acc[m][n], 0, 0, 0);
    }

#pragma unroll
    for (int n = 0; n < 4; ++n) {
        int col = colBase + n * 16 + lr;
#pragma unroll
        for (int m = 0; m < 4; ++m)
#pragma unroll
            for (int i = 0; i < 4; ++i) {
                int row = rowBase + m * 16 + lg * 4 + i;
                outb[(size_t)row * 512 + col] = __float2bfloat16(acc[m][n][i]);
            }
    }
}

// ---------------- flash-style fused attention ----------------
// grid 1024: bh = blk & 127 (-> XCD = bh%8, all 8 q-tiles of a (b,h) share an XCD's L2),
// qt = blk >> 7. Block = 4 waves; wave w owns q-rows [q0+16w, q0+16w+16).
// Runtime loop over k64 tiles (trip qt+1, block-uniform). K/V tiles staged in LDS via
// global_load_lds (16B) with pre-swizzled global source (col16 ^= row&7) -> conflict-free
// ds_read_b128 fragments. Online softmax in registers; P transposed via per-wave LDS.
__global__ __launch_bounds__(256, 3) void attn2_kernel(const __hip_bfloat16* __restrict__ Q,
                                                       const __hip_bfloat16* __restrict__ Km,
                                                       const __hip_bfloat16* __restrict__ VT,
                                                       const __hip_bfloat16* __restrict__ memv,
                                                       const float* __restrict__ l1,
                                                       __hip_bfloat16* __restrict__ outb) {
    __shared__ short lds[20480];          // K dbuf 8192 | V dbuf 8192 | P 4x1024 = 40KB
    short* Kb = lds;
    short* Vb = lds + 8192;
    int tid = threadIdx.x;
    int w = tid >> 6, l = tid & 63;
    int lr = l & 15, lg = l >> 4;
    int blk = blockIdx.x;
    int bh = blk & 127, qt = blk >> 7;
    int b = bh >> 3, h = bh & 7;
    int q0 = qt * 64;
    int nt = qt + 1;
    short* Pw = lds + 16384 + w * 1024;   // per-wave 16x64 bf16 (swizzled)

    const char* Kg = (const char*)Km + (size_t)bh * 65536;
    const char* Vg = (const char*)VT + (size_t)bh * 65536;

    // per-lane staging geometry (slot o in 16B units)
    int o0 = w * 64 + l;                  // chunk 0 slot
    // Q fragment (global, read once)
    const __hip_bfloat16* qp = Q + ((size_t)bh * 512 + q0 + w * 16 + lr) * 64 + lg * 8;
    bf16x8 qa0 = ldbf8(qp), qa1 = ldbf8(qp + 32);
    float lam = l1[0];

    // stage tile 0
#pragma unroll
    for (int c = 0; c < 2; ++c) {
        int o = c * 256 + o0;
        int r = o >> 3, c16 = o & 7;
        int sw = ((c16 ^ (r & 7)) << 4);
        gload_lds16(Kg + r * 128 + sw, (char*)Kb + o * 16);
        gload_lds16(Vg + r * 1024 + sw, (char*)Vb + o * 16);
    }
    __syncthreads();

    f32x4 acc2[4];
#pragma unroll
    for (int n = 0; n < 4; ++n) acc2[n] = (f32x4){0.f, 0.f, 0.f, 0.f};
    float mrun[4] = {-3e38f, -3e38f, -3e38f, -3e38f};
    float psum[4] = {0.f, 0.f, 0.f, 0.f};

    for (int t = 0; t < nt; ++t) {
        // prefetch next tile
        if (t + 1 < nt) {
#pragma unroll
            for (int c = 0; c < 2; ++c) {
                int o = c * 256 + o0;
                int r = o >> 3, c16 = o & 7;
                int sw = ((c16 ^ (r & 7)) << 4);
                gload_lds16(Kg + (t + 1) * 8192 + r * 128 + sw,
                            (char*)Kb + ((t + 1) & 1) * 8192 + o * 16);
                gload_lds16(Vg + r * 1024 + (t + 1) * 128 + sw,
                            (char*)Vb + ((t + 1) & 1) * 8192 + o * 16);
            }
        }
        const short* kb = Kb + (t & 1) * 4096;
        const short* vb = Vb + (t & 1) * 4096;

        // QK^T for this 64-col tile
        f32x4 s4[4];
#pragma unroll
        for (int j = 0; j < 4; ++j) {
            int row = j * 16 + lr;
            int sw = row & 7;
            bf16x8 k0 = *reinterpret_cast<const bf16x8*>(kb + row * 64 + ((lg ^ sw) << 3));
            bf16x8 k1 = *reinterpret_cast<const bf16x8*>(kb + row * 64 + (((4 + lg) ^ sw) << 3));
            f32x4 cc = {0.f, 0.f, 0.f, 0.f};
            cc = __builtin_amdgcn_mfma_f32_16x16x32_bf16(qa0, k0, cc, 0, 0, 0);
            cc = __builtin_amdgcn_mfma_f32_16x16x32_bf16(qa1, k1, cc, 0, 0, 0);
            s4[j] = cc;
        }

        // scale + (last-tile) causal mask
        if (t == nt - 1) {
#pragma unroll
            for (int j = 0; j < 4; ++j) {
                int col = t * 64 + j * 16 + lr;
#pragma unroll
                for (int i = 0; i < 4; ++i) {
                    int rowg = q0 + w * 16 + lg * 4 + i;
                    s4[j][i] = (col <= rowg) ? s4[j][i] * 0.125f : -3e38f;
                }
            }
        } else {
#pragma unroll
            for (int j = 0; j < 4; ++j)
#pragma unroll
                for (int i = 0; i < 4; ++i) s4[j][i] *= 0.125f;
        }

        // online softmax update
        float tmax[4];
#pragma unroll
        for (int i = 0; i < 4; ++i)
            tmax[i] = fmaxf(fmaxf(s4[0][i], s4[1][i]), fmaxf(s4[2][i], s4[3][i]));
#pragma unroll
        for (int off = 1; off < 16; off <<= 1)
#pragma unroll
            for (int i = 0; i < 4; ++i) tmax[i] = fmaxf(tmax[i], __shfl_xor(tmax[i], off));

        float e[4][4];
#pragma unroll
        for (int i = 0; i < 4; ++i) {
            float mnew = fmaxf(mrun[i], tmax[i]);
            float sc = __expf(mrun[i] - mnew);
            mrun[i] = mnew;
            float ps = 0.f;
#pragma unroll
            for (int j = 0; j < 4; ++j) {
                float ee = __expf(s4[j][i] - mnew);
                e[j][i] = ee;
                ps += ee;
            }
            psum[i] = psum[i] * sc + ps;
#pragma unroll
            for (int n = 0; n < 4; ++n) acc2[n][i] *= sc;
        }

        // write P (bf16) to per-wave LDS, swizzled
#pragma unroll
        for (int j = 0; j < 4; ++j)
#pragma unroll
            for (int i = 0; i < 4; ++i) {
                int rr = lg * 4 + i;
                int cc = j * 16 + lr;
                Pw[rr * 64 + (cc ^ ((rr & 7) << 3))] = (short)bfbits(e[j][i]);
            }

        // PV MFMA (P from LDS, V from staged LDS tile)
#pragma unroll
        for (int ksub = 0; ksub < 2; ++ksub) {
            bf16x8 pa = *reinterpret_cast<const bf16x8*>(
                Pw + lr * 64 + (((ksub * 4 + lg) ^ (lr & 7)) << 3));
#pragma unroll
            for (int n = 0; n < 4; ++n) {
                int d = n * 16 + lr;
                bf16x8 vf = *reinterpret_cast<const bf16x8*>(
                    vb + d * 64 + (((ksub * 4 + lg) ^ (d & 7)) << 3));
                acc2[n] = __builtin_amdgcn_mfma_f32_16x16x32_bf16(pa, vf, acc2[n], 0, 0, 0);
            }
        }
        __syncthreads();
    }

    // final row-sum reduce + normalize + blend with memv
#pragma unroll
    for (int off = 1; off < 16; off <<= 1)
#pragma unroll
        for (int i = 0; i < 4; ++i) psum[i] += __shfl_xor(psum[i], off);
    float rinv[4];
#pragma unroll
    for (int i = 0; i < 4; ++i) rinv[i] = (1.0f - lam) / psum[i];

    const __hip_bfloat16* mvp = memv + ((size_t)b * 512 + q0 + w * 16 + lg * 4) * 512 + h * 64;
    __hip_bfloat16* op = outb + ((size_t)b * 512 + q0 + w * 16 + lg * 4) * 512 + h * 64;
#pragma unroll
    for (int n = 0; n < 4; ++n)
#pragma unroll
        for (int i = 0; i < 4; ++i) {
            float mv = __bfloat162float(mvp[(size_t)i * 512 + n * 16 + lr]);
            op[(size_t)i * 512 + n * 16 + lr] =
                __float2bfloat16(acc2[n][i] * rinv[i] + lam * mv);
        }
}

// ---------------- LayerNorm (in-place on d_out) ----------------
__global__ __launch_bounds__(256) void ln_kernel(float* __restrict__ io,
                                                 const float* __restrict__ g,
                                                 const float* __restrict__ bb) {
    int tid = threadIdx.x;
    int w = tid >> 6, l = tid & 63;
    size_t row = (size_t)blockIdx.x * 4 + w;
    float* p = io + row * 512 + l * 8;
    float4 x0 = *reinterpret_cast<float4*>(p);
    float4 x1 = *reinterpret_cast<float4*>(p + 4);
    float xs[8] = {x0.x, x0.y, x0.z, x0.w, x1.x, x1.y, x1.z, x1.w};
    float s = 0.f;
#pragma unroll
    for (int j = 0; j < 8; ++j) s += xs[j];
#pragma unroll
    for (int off = 32; off >= 1; off >>= 1) s += __shfl_xor(s, off);
    float mu = s * (1.0f / 512.0f);
    float vs = 0.f;
#pragma unroll
    for (int j = 0; j < 8; ++j) { float d = xs[j] - mu; vs += d * d; }
#pragma unroll
    for (int off = 32; off >= 1; off >>= 1) vs += __shfl_xor(vs, off);
    float rstd = rsqrtf(vs * (1.0f / 512.0f) + 1e-5f);
    const float4 g0 = *reinterpret_cast<const float4*>(g + l * 8);
    const float4 g1 = *reinterpret_cast<const float4*>(g + l * 8 + 4);
    const float4 b0 = *reinterpret_cast<const float4*>(bb + l * 8);
    const float4 b1 = *reinterpret_cast<const float4*>(bb + l * 8 + 4);
    float gs[8] = {g0.x, g0.y, g0.z, g0.w, g1.x, g1.y, g1.z, g1.w};
    float bs[8] = {b0.x, b0.y, b0.z, b0.w, b1.x, b1.y, b1.z, b1.w};
    float ys[8];
#pragma unroll
    for (int j = 0; j < 8; ++j) ys[j] = (xs[j] - mu) * rstd * gs[j] + bs[j];
    float4 y0 = make_float4(ys[0], ys[1], ys[2], ys[3]);
    float4 y1 = make_float4(ys[4], ys[5], ys[6], ys[7]);
    *reinterpret_cast<float4*>(p) = y0;
    *reinterpret_cast<float4*>(p + 4) = y1;
}

// ---------------- host ----------------
extern "C" void kernel_launch(void* const* d_in, const int* in_sizes, int n_in,
                              void* d_out, int out_size, void* d_ws, size_t ws_size,
                              hipStream_t stream) {
    const float* inputs = (const float*)d_in[1];
    const float* ren    = (const float*)d_in[2];
    const float* ts     = (const float*)d_in[3];
    const float* Wq = (const float*)d_in[5];
    const float* bq = (const float*)d_in[6];
    const float* Wk = (const float*)d_in[7];
    const float* bk = (const float*)d_in[8];
    const float* Wv = (const float*)d_in[9];
    const float* bv = (const float*)d_in[10];
    const float* Wo = (const float*)d_in[11];
    const float* bo = (const float*)d_in[12];
    const float* W1 = (const float*)d_in[13];
    const float* b1 = (const float*)d_in[14];
    const float* ln_g = (const float*)d_in[15];
    const float* ln_b = (const float*)d_in[16];
    const float* l1   = (const float*)d_in[17];
    float* out = (float*)d_out;

    char* ws = (char*)d_ws;
    __hip_bfloat16* in_bf = (__hip_bfloat16*)(ws + 0);
    __hip_bfloat16* ao_bf = (__hip_bfloat16*)(ws + 0);          // reuse after projections
    __hip_bfloat16* wq_bf = (__hip_bfloat16*)(ws + 8388608);    // [wq|wk|wv|wo|w1] contiguous
    __hip_bfloat16* wo_bf = (__hip_bfloat16*)(ws + 9961472);
    __hip_bfloat16* w1_bf = (__hip_bfloat16*)(ws + 10485760);
    __hip_bfloat16* q_bf  = (__hip_bfloat16*)(ws + 11010048);
    __hip_bfloat16* o1_bf = (__hip_bfloat16*)(ws + 11010048);   // reuse after attn
    __hip_bfloat16* k_bf  = (__hip_bfloat16*)(ws + 19398656);
    __hip_bfloat16* vT_bf = (__hip_bfloat16*)(ws + 27787264);
    __hip_bfloat16* mem_bf = (__hip_bfloat16*)(ws + 36175872);
    float*          out1_f = (float*)(ws + 36175872);           // reuse after memv
    __hip_bfloat16* memv_bf = (__hip_bfloat16*)(ws + 69730304);

    // 1) convert inputs + weights to bf16
    cvt_kernel<<<4096, 256, 0, stream>>>(inputs, in_bf, BS * D / 4);
    wcvt_kernel<<<1280, 256, 0, stream>>>(Wq, Wk, Wv, Wo, W1, wq_bf);

    // 2) merged q/k/v projections
    gemm_qkv<<<dim3(64, 12), 256, 0, stream>>>(in_bf, wq_bf, bq, bk, bv, q_bf, k_bf, vT_bf);

    // 3) memory attention (head-independent, bf16, exact zeros in masked region)
    mem_attn_kernel<<<BS / 4, 256, 0, stream>>>(ren, ts, mem_bf);

    // 4) memV = mem @ V
    gemm_memv<<<dim3(64, 4), 256, 0, stream>>>(mem_bf, vT_bf, memv_bf);

    // 5) flash attention: (1-lam)*softmax(QK^T)@V + lam*memV
    attn2_kernel<<<1024, 256, 0, stream>>>(q_bf, k_bf, vT_bf, memv_bf, l1, ao_bf);

    // 6) output projection (fp32 + bf16 copies)
    gemm_bt<2><<<dim3(64, 4), 256, 0, stream>>>(ao_bf, wo_bf, bo, out1_f, o1_bf, nullptr);

    // 7) FFN + residual -> d_out (fp32)
    gemm_bt<3><<<dim3(64, 4), 256, 0, stream>>>(o1_bf, w1_bf, b1, out, nullptr, out1_f);

    // 8) LayerNorm in-place on d_out
    ln_kernel<<<BS / 4, 256, 0, stream>>>(out, ln_g, ln_b);
}

// Round 9
// 257.329 us; speedup vs baseline: 1.4754x; 1.1187x over previous
//
#include <hip/hip_runtime.h>
#include <hip/hip_bf16.h>

// Problem constants (fixed shapes)
constexpr int B = 16, S = 512, D = 512, H = 8, HD = 64;
constexpr int BS = B * S;   // 8192 rows

typedef __attribute__((ext_vector_type(8))) short bf16x8;
typedef __attribute__((ext_vector_type(4))) float f32x4;

#define DEVI __device__ __forceinline__

DEVI bf16x8 ldbf8(const __hip_bfloat16* p) {
    return *reinterpret_cast<const bf16x8*>(p);
}

DEVI unsigned short bfbits(float f) {
    __hip_bfloat16 h = __float2bfloat16(f);
    return __builtin_bit_cast(unsigned short, h);
}

DEVI void gload_lds16(const void* g, void* l) {
    __builtin_amdgcn_global_load_lds((const __attribute__((address_space(1))) void*)g,
                                     (__attribute__((address_space(3))) void*)l, 16, 0, 0);
}

// ---------------- fp32 -> bf16 conversion (vectorized) ----------------
__global__ __launch_bounds__(256) void cvt_kernel(const float* __restrict__ src,
                                                  __hip_bfloat16* __restrict__ dst,
                                                  int n4) {
    int i = blockIdx.x * 256 + threadIdx.x;
    if (i >= n4) return;
    float4 v = reinterpret_cast<const float4*>(src)[i];
    unsigned int lo = (unsigned int)bfbits(v.x) | ((unsigned int)bfbits(v.y) << 16);
    unsigned int hi = (unsigned int)bfbits(v.z) | ((unsigned int)bfbits(v.w) << 16);
    uint2 o; o.x = lo; o.y = hi;
    reinterpret_cast<uint2*>(dst)[i] = o;
}

// All 5 weight matrices (contiguous dst region) in one launch.
__global__ __launch_bounds__(256) void wcvt_kernel(const float* __restrict__ s0,
                                                   const float* __restrict__ s1,
                                                   const float* __restrict__ s2,
                                                   const float* __restrict__ s3,
                                                   const float* __restrict__ s4,
                                                   __hip_bfloat16* __restrict__ dst) {
    int idx = blockIdx.x * 256 + threadIdx.x;      // [0, 5*65536)
    int wsel = idx >> 16;                          // uniform per block
    int off = idx & 65535;
    const float* s;
    switch (wsel) {
        case 0: s = s0; break;
        case 1: s = s1; break;
        case 2: s = s2; break;
        case 3: s = s3; break;
        default: s = s4; break;
    }
    float4 v = reinterpret_cast<const float4*>(s)[off];
    unsigned int lo = (unsigned int)bfbits(v.x) | ((unsigned int)bfbits(v.y) << 16);
    unsigned int hi = (unsigned int)bfbits(v.z) | ((unsigned int)bfbits(v.w) << 16);
    uint2 o; o.x = lo; o.y = hi;
    reinterpret_cast<uint2*>(dst)[idx] = o;
}

// ---------------- mem_attn: softmax over log10(ren+1)+exp(-|ts|), causal ----------------
__global__ __launch_bounds__(256) void mem_attn_kernel(const float* __restrict__ ren,
                                                       const float* __restrict__ ts,
                                                       __hip_bfloat16* __restrict__ mem) {
    int tid = threadIdx.x;
    int w = tid >> 6, l = tid & 63;
    int row = blockIdx.x * 4 + w;        // b*S + q
    int qr = row & (S - 1);
    size_t base = (size_t)row * S + l * 8;
    float f[8];
    bool active = (l * 8 <= qr);
    if (active) {
        float4 r0 = *reinterpret_cast<const float4*>(ren + base);
        float4 r1 = *reinterpret_cast<const float4*>(ren + base + 4);
        float4 t0 = *reinterpret_cast<const float4*>(ts + base);
        float4 t1 = *reinterpret_cast<const float4*>(ts + base + 4);
        float rv[8] = {r0.x, r0.y, r0.z, r0.w, r1.x, r1.y, r1.z, r1.w};
        float tv[8] = {t0.x, t0.y, t0.z, t0.w, t1.x, t1.y, t1.z, t1.w};
#pragma unroll
        for (int j = 0; j < 8; ++j) {
            int c = l * 8 + j;
            f[j] = (c <= qr) ? (__log2f(rv[j] + 1.0f) * 0.3010299957f + __expf(-fabsf(tv[j])))
                             : -3.0e38f;
        }
    } else {
#pragma unroll
        for (int j = 0; j < 8; ++j) f[j] = -3.0e38f;
    }
    float m = -3.0e38f;
#pragma unroll
    for (int j = 0; j < 8; ++j) m = fmaxf(m, f[j]);
#pragma unroll
    for (int off = 32; off >= 1; off >>= 1) m = fmaxf(m, __shfl_xor(m, off));
    float s = 0.f;
#pragma unroll
    for (int j = 0; j < 8; ++j) { float e = __expf(f[j] - m); f[j] = e; s += e; }
#pragma unroll
    for (int off = 32; off >= 1; off >>= 1) s += __shfl_xor(s, off);
    float inv = 1.0f / s;
    bf16x8 o;
#pragma unroll
    for (int j = 0; j < 8; ++j) o[j] = (short)bfbits(f[j] * inv);
    *reinterpret_cast<bf16x8*>(mem + base) = o;
}

// ================= staged GEMM machinery (m97-style) =================
// Block tile 128x128, K-step 32, 4 waves 2x2 (wave tile 64x64, 4x4 MFMA 16x16x32).
// K-tiles staged to LDS via global_load_lds (16B), chunk-major layout
// [4 kchunks][128 rows][16B] so fragment ds_read_b128 is linear. Double-buffered:
// 2 x (8KB A + 8KB B) = 32 KB. 2-phase: STAGE(t+1) -> ds_read/MFMA(t) -> barrier.

DEVI void stage_tiles(const __hip_bfloat16* __restrict__ A,
                      const __hip_bfloat16* __restrict__ W,
                      int rowBase, int colBase, int kt, short* ldsbuf, int tid) {
#pragma unroll
    for (int c = 0; c < 2; ++c) {
        int o = c * 256 + tid;
        int row = o & 127, ch = o >> 7;
        gload_lds16(A + (size_t)(rowBase + row) * 512 + kt * 32 + ch * 8,
                    (char*)ldsbuf + o * 16);
        gload_lds16(W + (size_t)(colBase + row) * 512 + kt * 32 + ch * 8,
                    (char*)ldsbuf + 8192 + o * 16);
    }
}

DEVI void gemm_mainloop(const __hip_bfloat16* __restrict__ A,
                        const __hip_bfloat16* __restrict__ W,
                        int rowBase, int colBase, int ktiles,
                        short* lds, f32x4 (&acc)[4][4]) {
    int tid = threadIdx.x;
    int w = tid >> 6, l = tid & 63, lr = l & 15, lg = l >> 4;
    int wR = w >> 1, wC = w & 1;
    stage_tiles(A, W, rowBase, colBase, 0, lds, tid);
    __syncthreads();
    for (int t = 0; t < ktiles; ++t) {
        if (t + 1 < ktiles)
            stage_tiles(A, W, rowBase, colBase, t + 1, lds + ((t + 1) & 1) * 8192, tid);
        const short* ab = lds + (t & 1) * 8192;
        const short* bb = ab + 4096;
        bf16x8 af[4], bfr[4];
#pragma unroll
        for (int m = 0; m < 4; ++m)
            af[m] = *reinterpret_cast<const bf16x8*>(ab + (lg * 128 + wR * 64 + m * 16 + lr) * 8);
#pragma unroll
        for (int n = 0; n < 4; ++n)
            bfr[n] = *reinterpret_cast<const bf16x8*>(bb + (lg * 128 + wC * 64 + n * 16 + lr) * 8);
#pragma unroll
        for (int m = 0; m < 4; ++m)
#pragma unroll
            for (int n = 0; n < 4; ++n)
                acc[m][n] = __builtin_amdgcn_mfma_f32_16x16x32_bf16(af[m], bfr[n], acc[m][n], 0, 0, 0);
        __syncthreads();
    }
}

// ---------------- merged q/k/v projection (staged) ----------------
// grid (64, 12): y -> mat = y>>2 (0=q,1=k,2=v), col block = (y&3)*128.
// Epilogue: through per-wave LDS tile (XOR swizzle) -> fully coalesced b128 stores.
__global__ __launch_bounds__(256) void gemm_qkv_s(const __hip_bfloat16* __restrict__ A,
                                                  const __hip_bfloat16* __restrict__ Wqkv,
                                                  const float* __restrict__ bq,
                                                  const float* __restrict__ bk,
                                                  const float* __restrict__ bv,
                                                  __hip_bfloat16* __restrict__ q_out,
                                                  __hip_bfloat16* __restrict__ k_out,
                                                  __hip_bfloat16* __restrict__ vT_out) {
    __shared__ short lds[16384];   // 32 KB
    int tid = threadIdx.x;
    int w = tid >> 6, l = tid & 63, lr = l & 15, lg = l >> 4;
    int wR = w >> 1, wC = w & 1;
    int mat = blockIdx.y >> 2;
    int rowBase = blockIdx.x * 128;
    int colBase = (blockIdx.y & 3) * 128;
    const float* bias = (mat == 0) ? bq : (mat == 1) ? bk : bv;
    const __hip_bfloat16* W = Wqkv + (size_t)mat * 262144;

    f32x4 acc[4][4];
#pragma unroll
    for (int m = 0; m < 4; ++m)
#pragma unroll
        for (int n = 0; n < 4; ++n) acc[m][n] = (f32x4){0.f, 0.f, 0.f, 0.f};

    gemm_mainloop(A, W, rowBase, colBase, 16, lds, acc);
    // mainloop ends with a barrier -> lds reusable as per-wave epilogue tiles
    short* ep = lds + w * 4096;    // 64x64 bf16 per wave
    float bsv[4];
#pragma unroll
    for (int n = 0; n < 4; ++n) bsv[n] = bias[colBase + wC * 64 + n * 16 + lr];

    if (mat < 2) {
        // q/k -> (B,H,S,hd): tile rows = s, cols = d. Swizzled write, row read.
        __hip_bfloat16* o = (mat == 0) ? q_out : k_out;
#pragma unroll
        for (int m = 0; m < 4; ++m)
#pragma unroll
            for (int n = 0; n < 4; ++n)
#pragma unroll
                for (int i = 0; i < 4; ++i) {
                    int rr = m * 16 + lg * 4 + i, cl = n * 16 + lr;
                    ep[rr * 64 + (cl ^ ((rr & 7) << 3))] = (short)bfbits(acc[m][n][i] + bsv[n]);
                }
        int h_ = (colBase + wC * 64) >> 6;
#pragma unroll
        for (int p = 0; p < 8; ++p) {
            int rr = p * 8 + (l >> 3), ch = l & 7;
            bf16x8 v = *reinterpret_cast<const bf16x8*>(ep + rr * 64 + ((ch ^ (rr & 7)) << 3));
            int grow = rowBase + wR * 64 + rr;
            int b_ = grow >> 9, s_ = grow & 511;
            *reinterpret_cast<bf16x8*>(o + (((size_t)(b_ * 8 + h_) * 512 + s_) << 6) + ch * 8) = v;
        }
    } else {
        // v -> (B,H,hd,S): store tile TRANSPOSED into ep (rows = d, cols = s).
#pragma unroll
        for (int m = 0; m < 4; ++m)
#pragma unroll
            for (int n = 0; n < 4; ++n)
#pragma unroll
                for (int i = 0; i < 4; ++i) {
                    int ss = m * 16 + lg * 4 + i, dd = n * 16 + lr;
                    ep[dd * 64 + (ss ^ ((dd & 7) << 3))] = (short)bfbits(acc[m][n][i] + bsv[n]);
                }
        int h_ = (colBase + wC * 64) >> 6;
        int s0g = rowBase + wR * 64;
        int b_ = s0g >> 9, sb = s0g & 511;
#pragma unroll
        for (int p = 0; p < 8; ++p) {
            int dd = p * 8 + (l >> 3), ch = l & 7;
            bf16x8 v = *reinterpret_cast<const bf16x8*>(ep + dd * 64 + ((ch ^ (dd & 7)) << 3));
            *reinterpret_cast<bf16x8*>(vT_out + (((size_t)(b_ * 8 + h_) * 64 + dd) << 9) + sb + ch * 8) = v;
        }
    }
}

// ---------------- Wo / W1 epilogue GEMMs (staged mainloop, direct fp32 stores) ----------------
// MODE 2: store fp32 + bf16 row-major (Wo)
// MODE 3: store fp32 row-major, += resid (W1 + residual)
template <int MODE>
__global__ __launch_bounds__(256) void gemm_bt_s(const __hip_bfloat16* __restrict__ A,
                                                 const __hip_bfloat16* __restrict__ W,
                                                 const float* __restrict__ bias,
                                                 float* __restrict__ outf,
                                                 __hip_bfloat16* __restrict__ outb,
                                                 const float* __restrict__ resid) {
    __shared__ short lds[16384];
    int tid = threadIdx.x;
    int w = tid >> 6, l = tid & 63, lr = l & 15, lg = l >> 4;
    int wR = w >> 1, wC = w & 1;
    int rowBase = blockIdx.x * 128;
    int colBase = blockIdx.y * 128;

    f32x4 acc[4][4];
#pragma unroll
    for (int m = 0; m < 4; ++m)
#pragma unroll
        for (int n = 0; n < 4; ++n) acc[m][n] = (f32x4){0.f, 0.f, 0.f, 0.f};

    gemm_mainloop(A, W, rowBase, colBase, 16, lds, acc);

#pragma unroll
    for (int n = 0; n < 4; ++n) {
        int col = colBase + wC * 64 + n * 16 + lr;
        float bs = bias[col];
#pragma unroll
        for (int m = 0; m < 4; ++m) {
#pragma unroll
            for (int i = 0; i < 4; ++i) {
                int row = rowBase + wR * 64 + m * 16 + lg * 4 + i;
                float val = acc[m][n][i] + bs;
                size_t idx = (size_t)row * 512 + col;
                if constexpr (MODE == 2) {
                    outf[idx] = val;
                    outb[idx] = __float2bfloat16(val);
                } else {
                    outf[idx] = val + resid[idx];
                }
            }
        }
    }
}

// ---------------- memV GEMM (staged): memv[b,q,:] = mem[b,q,:] @ vT_b^T ----------------
// B-operand rows for col j are vT global row b*512 + j (contiguous per b).
// Triangular K clip per row-block. Coalesced bf16 epilogue through LDS.
__global__ __launch_bounds__(256) void gemm_memv_s(const __hip_bfloat16* __restrict__ A,
                                                   const __hip_bfloat16* __restrict__ VT,
                                                   __hip_bfloat16* __restrict__ outb) {
    __shared__ short lds[16384];
    int tid = threadIdx.x;
    int w = tid >> 6, l = tid & 63, lr = l & 15, lg = l >> 4;
    int wR = w >> 1, wC = w & 1;
    int rowBase = blockIdx.x * 128;
    int colBase = blockIdx.y * 128;
    int b_ = rowBase >> 9;
    const __hip_bfloat16* W = VT + (size_t)b_ * 262144;
    int ktiles = ((blockIdx.x & 3) + 1) * 4;

    f32x4 acc[4][4];
#pragma unroll
    for (int m = 0; m < 4; ++m)
#pragma unroll
        for (int n = 0; n < 4; ++n) acc[m][n] = (f32x4){0.f, 0.f, 0.f, 0.f};

    gemm_mainloop(A, W, rowBase, colBase, ktiles, lds, acc);

    short* ep = lds + w * 4096;
#pragma unroll
    for (int m = 0; m < 4; ++m)
#pragma unroll
        for (int n = 0; n < 4; ++n)
#pragma unroll
            for (int i = 0; i < 4; ++i) {
                int rr = m * 16 + lg * 4 + i, cl = n * 16 + lr;
                ep[rr * 64 + (cl ^ ((rr & 7) << 3))] = (short)bfbits(acc[m][n][i]);
            }
#pragma unroll
    for (int p = 0; p < 8; ++p) {
        int rr = p * 8 + (l >> 3), ch = l & 7;
        bf16x8 v = *reinterpret_cast<const bf16x8*>(ep + rr * 64 + ((ch ^ (rr & 7)) << 3));
        int grow = rowBase + wR * 64 + rr;
        *reinterpret_cast<bf16x8*>(outb + (size_t)grow * 512 + colBase + wC * 64 + ch * 8) = v;
    }
}

// ---------------- flash-style fused attention (unchanged from r3 -- verified) ----------------
__global__ __launch_bounds__(256, 3) void attn2_kernel(const __hip_bfloat16* __restrict__ Q,
                                                       const __hip_bfloat16* __restrict__ Km,
                                                       const __hip_bfloat16* __restrict__ VT,
                                                       const __hip_bfloat16* __restrict__ memv,
                                                       const float* __restrict__ l1,
                                                       __hip_bfloat16* __restrict__ outb) {
    __shared__ short lds[20480];          // K dbuf 8192 | V dbuf 8192 | P 4x1024 = 40KB
    short* Kb = lds;
    short* Vb = lds + 8192;
    int tid = threadIdx.x;
    int w = tid >> 6, l = tid & 63;
    int lr = l & 15, lg = l >> 4;
    int blk = blockIdx.x;
    int bh = blk & 127, qt = blk >> 7;
    int b = bh >> 3, h = bh & 7;
    int q0 = qt * 64;
    int nt = qt + 1;
    short* Pw = lds + 16384 + w * 1024;   // per-wave 16x64 bf16 (swizzled)

    const char* Kg = (const char*)Km + (size_t)bh * 65536;
    const char* Vg = (const char*)VT + (size_t)bh * 65536;

    int o0 = w * 64 + l;                  // chunk 0 slot
    const __hip_bfloat16* qp = Q + ((size_t)bh * 512 + q0 + w * 16 + lr) * 64 + lg * 8;
    bf16x8 qa0 = ldbf8(qp), qa1 = ldbf8(qp + 32);
    float lam = l1[0];

    // stage tile 0
#pragma unroll
    for (int c = 0; c < 2; ++c) {
        int o = c * 256 + o0;
        int r = o >> 3, c16 = o & 7;
        int sw = ((c16 ^ (r & 7)) << 4);
        gload_lds16(Kg + r * 128 + sw, (char*)Kb + o * 16);
        gload_lds16(Vg + r * 1024 + sw, (char*)Vb + o * 16);
    }
    __syncthreads();

    f32x4 acc2[4];
#pragma unroll
    for (int n = 0; n < 4; ++n) acc2[n] = (f32x4){0.f, 0.f, 0.f, 0.f};
    float mrun[4] = {-3e38f, -3e38f, -3e38f, -3e38f};
    float psum[4] = {0.f, 0.f, 0.f, 0.f};

    for (int t = 0; t < nt; ++t) {
        if (t + 1 < nt) {
#pragma unroll
            for (int c = 0; c < 2; ++c) {
                int o = c * 256 + o0;
                int r = o >> 3, c16 = o & 7;
                int sw = ((c16 ^ (r & 7)) << 4);
                gload_lds16(Kg + (t + 1) * 8192 + r * 128 + sw,
                            (char*)Kb + ((t + 1) & 1) * 8192 + o * 16);
                gload_lds16(Vg + r * 1024 + (t + 1) * 128 + sw,
                            (char*)Vb + ((t + 1) & 1) * 8192 + o * 16);
            }
        }
        const short* kb = Kb + (t & 1) * 4096;
        const short* vb = Vb + (t & 1) * 4096;

        f32x4 s4[4];
#pragma unroll
        for (int j = 0; j < 4; ++j) {
            int row = j * 16 + lr;
            int sw = row & 7;
            bf16x8 k0 = *reinterpret_cast<const bf16x8*>(kb + row * 64 + ((lg ^ sw) << 3));
            bf16x8 k1 = *reinterpret_cast<const bf16x8*>(kb + row * 64 + (((4 + lg) ^ sw) << 3));
            f32x4 cc = {0.f, 0.f, 0.f, 0.f};
            cc = __builtin_amdgcn_mfma_f32_16x16x32_bf16(qa0, k0, cc, 0, 0, 0);
            cc = __builtin_amdgcn_mfma_f32_16x16x32_bf16(qa1, k1, cc, 0, 0, 0);
            s4[j] = cc;
        }

        if (t == nt - 1) {
#pragma unroll
            for (int j = 0; j < 4; ++j) {
                int col = t * 64 + j * 16 + lr;
#pragma unroll
                for (int i = 0; i < 4; ++i) {
                    int rowg = q0 + w * 16 + lg * 4 + i;
                    s4[j][i] = (col <= rowg) ? s4[j][i] * 0.125f : -3e38f;
                }
            }
        } else {
#pragma unroll
            for (int j = 0; j < 4; ++j)
#pragma unroll
                for (int i = 0; i < 4; ++i) s4[j][i] *= 0.125f;
        }

        float tmax[4];
#pragma unroll
        for (int i = 0; i < 4; ++i)
            tmax[i] = fmaxf(fmaxf(s4[0][i], s4[1][i]), fmaxf(s4[2][i], s4[3][i]));
#pragma unroll
        for (int off = 1; off < 16; off <<= 1)
#pragma unroll
            for (int i = 0; i < 4; ++i) tmax[i] = fmaxf(tmax[i], __shfl_xor(tmax[i], off));

        float e[4][4];
#pragma unroll
        for (int i = 0; i < 4; ++i) {
            float mnew = fmaxf(mrun[i], tmax[i]);
            float sc = __expf(mrun[i] - mnew);
            mrun[i] = mnew;
            float ps = 0.f;
#pragma unroll
            for (int j = 0; j < 4; ++j) {
                float ee = __expf(s4[j][i] - mnew);
                e[j][i] = ee;
                ps += ee;
            }
            psum[i] = psum[i] * sc + ps;
#pragma unroll
            for (int n = 0; n < 4; ++n) acc2[n][i] *= sc;
        }

#pragma unroll
        for (int j = 0; j < 4; ++j)
#pragma unroll
            for (int i = 0; i < 4; ++i) {
                int rr = lg * 4 + i;
                int cc = j * 16 + lr;
                Pw[rr * 64 + (cc ^ ((rr & 7) << 3))] = (short)bfbits(e[j][i]);
            }

#pragma unroll
        for (int ksub = 0; ksub < 2; ++ksub) {
            bf16x8 pa = *reinterpret_cast<const bf16x8*>(
                Pw + lr * 64 + (((ksub * 4 + lg) ^ (lr & 7)) << 3));
#pragma unroll
            for (int n = 0; n < 4; ++n) {
                int d = n * 16 + lr;
                bf16x8 vf = *reinterpret_cast<const bf16x8*>(
                    vb + d * 64 + (((ksub * 4 + lg) ^ (d & 7)) << 3));
                acc2[n] = __builtin_amdgcn_mfma_f32_16x16x32_bf16(pa, vf, acc2[n], 0, 0, 0);
            }
        }
        __syncthreads();
    }

#pragma unroll
    for (int off = 1; off < 16; off <<= 1)
#pragma unroll
        for (int i = 0; i < 4; ++i) psum[i] += __shfl_xor(psum[i], off);
    float rinv[4];
#pragma unroll
    for (int i = 0; i < 4; ++i) rinv[i] = (1.0f - lam) / psum[i];

    const __hip_bfloat16* mvp = memv + ((size_t)b * 512 + q0 + w * 16 + lg * 4) * 512 + h * 64;
    __hip_bfloat16* op = outb + ((size_t)b * 512 + q0 + w * 16 + lg * 4) * 512 + h * 64;
#pragma unroll
    for (int n = 0; n < 4; ++n)
#pragma unroll
        for (int i = 0; i < 4; ++i) {
            float mv = __bfloat162float(mvp[(size_t)i * 512 + n * 16 + lr]);
            op[(size_t)i * 512 + n * 16 + lr] =
                __float2bfloat16(acc2[n][i] * rinv[i] + lam * mv);
        }
}

// ---------------- LayerNorm (in-place on d_out) ----------------
__global__ __launch_bounds__(256) void ln_kernel(float* __restrict__ io,
                                                 const float* __restrict__ g,
                                                 const float* __restrict__ bb) {
    int tid = threadIdx.x;
    int w = tid >> 6, l = tid & 63;
    size_t row = (size_t)blockIdx.x * 4 + w;
    float* p = io + row * 512 + l * 8;
    float4 x0 = *reinterpret_cast<float4*>(p);
    float4 x1 = *reinterpret_cast<float4*>(p + 4);
    float xs[8] = {x0.x, x0.y, x0.z, x0.w, x1.x, x1.y, x1.z, x1.w};
    float s = 0.f;
#pragma unroll
    for (int j = 0; j < 8; ++j) s += xs[j];
#pragma unroll
    for (int off = 32; off >= 1; off >>= 1) s += __shfl_xor(s, off);
    float mu = s * (1.0f / 512.0f);
    float vs = 0.f;
#pragma unroll
    for (int j = 0; j < 8; ++j) { float d = xs[j] - mu; vs += d * d; }
#pragma unroll
    for (int off = 32; off >= 1; off >>= 1) vs += __shfl_xor(vs, off);
    float rstd = rsqrtf(vs * (1.0f / 512.0f) + 1e-5f);
    const float4 g0 = *reinterpret_cast<const float4*>(g + l * 8);
    const float4 g1 = *reinterpret_cast<const float4*>(g + l * 8 + 4);
    const float4 b0 = *reinterpret_cast<const float4*>(bb + l * 8);
    const float4 b1 = *reinterpret_cast<const float4*>(bb + l * 8 + 4);
    float gs[8] = {g0.x, g0.y, g0.z, g0.w, g1.x, g1.y, g1.z, g1.w};
    float bs[8] = {b0.x, b0.y, b0.z, b0.w, b1.x, b1.y, b1.z, b1.w};
    float ys[8];
#pragma unroll
    for (int j = 0; j < 8; ++j) ys[j] = (xs[j] - mu) * rstd * gs[j] + bs[j];
    float4 y0 = make_float4(ys[0], ys[1], ys[2], ys[3]);
    float4 y1 = make_float4(ys[4], ys[5], ys[6], ys[7]);
    *reinterpret_cast<float4*>(p) = y0;
    *reinterpret_cast<float4*>(p + 4) = y1;
}

// ---------------- host ----------------
extern "C" void kernel_launch(void* const* d_in, const int* in_sizes, int n_in,
                              void* d_out, int out_size, void* d_ws, size_t ws_size,
                              hipStream_t stream) {
    const float* inputs = (const float*)d_in[1];
    const float* ren    = (const float*)d_in[2];
    const float* ts     = (const float*)d_in[3];
    const float* Wq = (const float*)d_in[5];
    const float* bq = (const float*)d_in[6];
    const float* Wk = (const float*)d_in[7];
    const float* bk = (const float*)d_in[8];
    const float* Wv = (const float*)d_in[9];
    const float* bv = (const float*)d_in[10];
    const float* Wo = (const float*)d_in[11];
    const float* bo = (const float*)d_in[12];
    const float* W1 = (const float*)d_in[13];
    const float* b1 = (const float*)d_in[14];
    const float* ln_g = (const float*)d_in[15];
    const float* ln_b = (const float*)d_in[16];
    const float* l1   = (const float*)d_in[17];
    float* out = (float*)d_out;

    char* ws = (char*)d_ws;
    __hip_bfloat16* in_bf = (__hip_bfloat16*)(ws + 0);
    __hip_bfloat16* ao_bf = (__hip_bfloat16*)(ws + 0);          // reuse after projections
    __hip_bfloat16* wq_bf = (__hip_bfloat16*)(ws + 8388608);    // [wq|wk|wv|wo|w1] contiguous
    __hip_bfloat16* wo_bf = (__hip_bfloat16*)(ws + 9961472);
    __hip_bfloat16* w1_bf = (__hip_bfloat16*)(ws + 10485760);
    __hip_bfloat16* q_bf  = (__hip_bfloat16*)(ws + 11010048);
    __hip_bfloat16* o1_bf = (__hip_bfloat16*)(ws + 11010048);   // reuse after attn
    __hip_bfloat16* k_bf  = (__hip_bfloat16*)(ws + 19398656);
    __hip_bfloat16* vT_bf = (__hip_bfloat16*)(ws + 27787264);
    __hip_bfloat16* mem_bf = (__hip_bfloat16*)(ws + 36175872);
    float*          out1_f = (float*)(ws + 36175872);           // reuse after memv
    __hip_bfloat16* memv_bf = (__hip_bfloat16*)(ws + 69730304);

    // 1) convert inputs + weights to bf16
    cvt_kernel<<<4096, 256, 0, stream>>>(inputs, in_bf, BS * D / 4);
    wcvt_kernel<<<1280, 256, 0, stream>>>(Wq, Wk, Wv, Wo, W1, wq_bf);

    // 2) merged q/k/v projections (staged)
    gemm_qkv_s<<<dim3(64, 12), 256, 0, stream>>>(in_bf, wq_bf, bq, bk, bv, q_bf, k_bf, vT_bf);

    // 3) memory attention (head-independent, bf16, exact zeros in masked region)
    mem_attn_kernel<<<BS / 4, 256, 0, stream>>>(ren, ts, mem_bf);

    // 4) memV = mem @ V (staged, triangular K clip)
    gemm_memv_s<<<dim3(64, 4), 256, 0, stream>>>(mem_bf, vT_bf, memv_bf);

    // 5) flash attention: (1-lam)*softmax(QK^T)@V + lam*memV
    attn2_kernel<<<1024, 256, 0, stream>>>(q_bf, k_bf, vT_bf, memv_bf, l1, ao_bf);

    // 6) output projection (staged; fp32 + bf16 copies)
    gemm_bt_s<2><<<dim3(64, 4), 256, 0, stream>>>(ao_bf, wo_bf, bo, out1_f, o1_bf, nullptr);

    // 7) FFN + residual -> d_out (staged, fp32)
    gemm_bt_s<3><<<dim3(64, 4), 256, 0, stream>>>(o1_bf, w1_bf, b1, out, nullptr, out1_f);

    // 8) LayerNorm in-place on d_out
    ln_kernel<<<BS / 4, 256, 0, stream>>>(out, ln_g, ln_b);
}

// Round 11
// 253.781 us; speedup vs baseline: 1.4960x; 1.0140x over previous
//
#include <hip/hip_runtime.h>
#include <hip/hip_bf16.h>

// Problem constants (fixed shapes)
constexpr int B = 16, S = 512, D = 512, H = 8, HD = 64;
constexpr int BS = B * S;   // 8192 rows

typedef __attribute__((ext_vector_type(8))) short bf16x8;
typedef __attribute__((ext_vector_type(4))) float f32x4;

#define DEVI __device__ __forceinline__

DEVI bf16x8 ldbf8(const __hip_bfloat16* p) {
    return *reinterpret_cast<const bf16x8*>(p);
}

DEVI unsigned short bfbits(float f) {
    __hip_bfloat16 h = __float2bfloat16(f);
    return __builtin_bit_cast(unsigned short, h);
}

DEVI void gload_lds16(const void* g, void* l) {
    __builtin_amdgcn_global_load_lds((const __attribute__((address_space(1))) void*)g,
                                     (__attribute__((address_space(3))) void*)l, 16, 0, 0);
}

// ---------------- fp32 -> bf16 conversion (vectorized) ----------------
__global__ __launch_bounds__(256) void cvt_kernel(const float* __restrict__ src,
                                                  __hip_bfloat16* __restrict__ dst,
                                                  int n4) {
    int i = blockIdx.x * 256 + threadIdx.x;
    if (i >= n4) return;
    float4 v = reinterpret_cast<const float4*>(src)[i];
    unsigned int lo = (unsigned int)bfbits(v.x) | ((unsigned int)bfbits(v.y) << 16);
    unsigned int hi = (unsigned int)bfbits(v.z) | ((unsigned int)bfbits(v.w) << 16);
    uint2 o; o.x = lo; o.y = hi;
    reinterpret_cast<uint2*>(dst)[i] = o;
}

// 4 weight matrices [Wq|Wk|Wv|W1] -> contiguous bf16 region.
__global__ __launch_bounds__(256) void wcvt4_kernel(const float* __restrict__ s0,
                                                    const float* __restrict__ s1,
                                                    const float* __restrict__ s2,
                                                    const float* __restrict__ s3,
                                                    __hip_bfloat16* __restrict__ dst) {
    int idx = blockIdx.x * 256 + threadIdx.x;      // [0, 4*65536)
    int wsel = idx >> 16;                          // uniform per block
    int off = idx & 65535;
    const float* s;
    switch (wsel) {
        case 0: s = s0; break;
        case 1: s = s1; break;
        case 2: s = s2; break;
        default: s = s3; break;
    }
    float4 v = reinterpret_cast<const float4*>(s)[off];
    unsigned int lo = (unsigned int)bfbits(v.x) | ((unsigned int)bfbits(v.y) << 16);
    unsigned int hi = (unsigned int)bfbits(v.z) | ((unsigned int)bfbits(v.w) << 16);
    uint2 o; o.x = lo; o.y = hi;
    reinterpret_cast<uint2*>(dst)[idx] = o;
}

// Transpose-convert: WoT[k][m] = bf16(Wo[m][k]). grid 64 (8x8 64-tiles), block 256.
__global__ __launch_bounds__(256) void wtr_kernel(const float* __restrict__ Wo,
                                                  __hip_bfloat16* __restrict__ WoT) {
    __shared__ float t64[64][65];
    int bx = blockIdx.x & 7, by = blockIdx.x >> 3;   // k-tile, m-tile
    int tc = threadIdx.x & 63, tr = threadIdx.x >> 6;
#pragma unroll
    for (int i = 0; i < 16; ++i) {
        int row = tr * 16 + i;
        t64[row][tc] = Wo[(size_t)(by * 64 + row) * 512 + bx * 64 + tc];
    }
    __syncthreads();
#pragma unroll
    for (int i = 0; i < 16; ++i) {
        int row = tr * 16 + i;    // k within tile
        WoT[(size_t)(bx * 64 + row) * 512 + by * 64 + tc] = __float2bfloat16(t64[tc][row]);
    }
}

// b_eff[j] = bo[j] + sum_m W1[j,m]*bo[m] + b1[j]. grid 2, block 256.
__global__ __launch_bounds__(256) void bprep_kernel(const float* __restrict__ W1,
                                                    const float* __restrict__ bo,
                                                    const float* __restrict__ b1,
                                                    float* __restrict__ beff) {
    int j = blockIdx.x * 256 + threadIdx.x;
    float s = 0.f;
    const float4* wr = reinterpret_cast<const float4*>(W1 + (size_t)j * 512);
    const float4* br = reinterpret_cast<const float4*>(bo);
    for (int m = 0; m < 128; ++m) {
        float4 a = wr[m], b = br[m];
        s += a.x * b.x + a.y * b.y + a.z * b.z + a.w * b.w;
    }
    beff[j] = bo[j] + s + b1[j];
}

// ---------------- mem_attn: softmax over log10(ren+1)+exp(-|ts|), causal ----------------
__global__ __launch_bounds__(256) void mem_attn_kernel(const float* __restrict__ ren,
                                                       const float* __restrict__ ts,
                                                       __hip_bfloat16* __restrict__ mem) {
    int tid = threadIdx.x;
    int w = tid >> 6, l = tid & 63;
    int row = blockIdx.x * 4 + w;        // b*S + q
    int qr = row & (S - 1);
    size_t base = (size_t)row * S + l * 8;
    float f[8];
    bool active = (l * 8 <= qr);
    if (active) {
        float4 r0 = *reinterpret_cast<const float4*>(ren + base);
        float4 r1 = *reinterpret_cast<const float4*>(ren + base + 4);
        float4 t0 = *reinterpret_cast<const float4*>(ts + base);
        float4 t1 = *reinterpret_cast<const float4*>(ts + base + 4);
        float rv[8] = {r0.x, r0.y, r0.z, r0.w, r1.x, r1.y, r1.z, r1.w};
        float tv[8] = {t0.x, t0.y, t0.z, t0.w, t1.x, t1.y, t1.z, t1.w};
#pragma unroll
        for (int j = 0; j < 8; ++j) {
            int c = l * 8 + j;
            f[j] = (c <= qr) ? (__log2f(rv[j] + 1.0f) * 0.3010299957f + __expf(-fabsf(tv[j])))
                             : -3.0e38f;
        }
    } else {
#pragma unroll
        for (int j = 0; j < 8; ++j) f[j] = -3.0e38f;
    }
    float m = -3.0e38f;
#pragma unroll
    for (int j = 0; j < 8; ++j) m = fmaxf(m, f[j]);
#pragma unroll
    for (int off = 32; off >= 1; off >>= 1) m = fmaxf(m, __shfl_xor(m, off));
    float s = 0.f;
#pragma unroll
    for (int j = 0; j < 8; ++j) { float e = __expf(f[j] - m); f[j] = e; s += e; }
#pragma unroll
    for (int off = 32; off >= 1; off >>= 1) s += __shfl_xor(s, off);
    float inv = 1.0f / s;
    bf16x8 o;
#pragma unroll
    for (int j = 0; j < 8; ++j) o[j] = (short)bfbits(f[j] * inv);
    *reinterpret_cast<bf16x8*>(mem + base) = o;
}

// ================= staged GEMM machinery (m97-style) =================
DEVI void stage_tiles(const __hip_bfloat16* __restrict__ A,
                      const __hip_bfloat16* __restrict__ W,
                      int rowBase, int colBase, int kt, short* ldsbuf, int tid) {
#pragma unroll
    for (int c = 0; c < 2; ++c) {
        int o = c * 256 + tid;
        int row = o & 127, ch = o >> 7;
        gload_lds16(A + (size_t)(rowBase + row) * 512 + kt * 32 + ch * 8,
                    (char*)ldsbuf + o * 16);
        gload_lds16(W + (size_t)(colBase + row) * 512 + kt * 32 + ch * 8,
                    (char*)ldsbuf + 8192 + o * 16);
    }
}

DEVI void gemm_mainloop(const __hip_bfloat16* __restrict__ A,
                        const __hip_bfloat16* __restrict__ W,
                        int rowBase, int colBase, int ktiles,
                        short* lds, f32x4 (&acc)[4][4]) {
    int tid = threadIdx.x;
    int w = tid >> 6, l = tid & 63, lr = l & 15, lg = l >> 4;
    int wR = w >> 1, wC = w & 1;
    stage_tiles(A, W, rowBase, colBase, 0, lds, tid);
    __syncthreads();
    for (int t = 0; t < ktiles; ++t) {
        if (t + 1 < ktiles)
            stage_tiles(A, W, rowBase, colBase, t + 1, lds + ((t + 1) & 1) * 8192, tid);
        const short* ab = lds + (t & 1) * 8192;
        const short* bb = ab + 4096;
        bf16x8 af[4], bfr[4];
#pragma unroll
        for (int m = 0; m < 4; ++m)
            af[m] = *reinterpret_cast<const bf16x8*>(ab + (lg * 128 + wR * 64 + m * 16 + lr) * 8);
#pragma unroll
        for (int n = 0; n < 4; ++n)
            bfr[n] = *reinterpret_cast<const bf16x8*>(bb + (lg * 128 + wC * 64 + n * 16 + lr) * 8);
#pragma unroll
        for (int m = 0; m < 4; ++m)
#pragma unroll
            for (int n = 0; n < 4; ++n)
                acc[m][n] = __builtin_amdgcn_mfma_f32_16x16x32_bf16(af[m], bfr[n], acc[m][n], 0, 0, 0);
        __syncthreads();
    }
}

// ---------------- merged q/k/v projection (staged) ----------------
__global__ __launch_bounds__(256) void gemm_qkv_s(const __hip_bfloat16* __restrict__ A,
                                                  const __hip_bfloat16* __restrict__ Wqkv,
                                                  const float* __restrict__ bq,
                                                  const float* __restrict__ bk,
                                                  const float* __restrict__ bv,
                                                  __hip_bfloat16* __restrict__ q_out,
                                                  __hip_bfloat16* __restrict__ k_out,
                                                  __hip_bfloat16* __restrict__ vT_out) {
    __shared__ short lds[16384];   // 32 KB
    int tid = threadIdx.x;
    int w = tid >> 6, l = tid & 63, lr = l & 15, lg = l >> 4;
    int wR = w >> 1, wC = w & 1;
    int mat = blockIdx.y >> 2;
    int rowBase = blockIdx.x * 128;
    int colBase = (blockIdx.y & 3) * 128;
    const float* bias = (mat == 0) ? bq : (mat == 1) ? bk : bv;
    const __hip_bfloat16* W = Wqkv + (size_t)mat * 262144;

    f32x4 acc[4][4];
#pragma unroll
    for (int m = 0; m < 4; ++m)
#pragma unroll
        for (int n = 0; n < 4; ++n) acc[m][n] = (f32x4){0.f, 0.f, 0.f, 0.f};

    gemm_mainloop(A, W, rowBase, colBase, 16, lds, acc);
    short* ep = lds + w * 4096;    // 64x64 bf16 per wave
    float bsv[4];
#pragma unroll
    for (int n = 0; n < 4; ++n) bsv[n] = bias[colBase + wC * 64 + n * 16 + lr];

    if (mat < 2) {
        __hip_bfloat16* o = (mat == 0) ? q_out : k_out;
#pragma unroll
        for (int m = 0; m < 4; ++m)
#pragma unroll
            for (int n = 0; n < 4; ++n)
#pragma unroll
                for (int i = 0; i < 4; ++i) {
                    int rr = m * 16 + lg * 4 + i, cl = n * 16 + lr;
                    ep[rr * 64 + (cl ^ ((rr & 7) << 3))] = (short)bfbits(acc[m][n][i] + bsv[n]);
                }
        int h_ = (colBase + wC * 64) >> 6;
#pragma unroll
        for (int p = 0; p < 8; ++p) {
            int rr = p * 8 + (l >> 3), ch = l & 7;
            bf16x8 v = *reinterpret_cast<const bf16x8*>(ep + rr * 64 + ((ch ^ (rr & 7)) << 3));
            int grow = rowBase + wR * 64 + rr;
            int b_ = grow >> 9, s_ = grow & 511;
            *reinterpret_cast<bf16x8*>(o + (((size_t)(b_ * 8 + h_) * 512 + s_) << 6) + ch * 8) = v;
        }
    } else {
#pragma unroll
        for (int m = 0; m < 4; ++m)
#pragma unroll
            for (int n = 0; n < 4; ++n)
#pragma unroll
                for (int i = 0; i < 4; ++i) {
                    int ss = m * 16 + lg * 4 + i, dd = n * 16 + lr;
                    ep[dd * 64 + (ss ^ ((dd & 7) << 3))] = (short)bfbits(acc[m][n][i] + bsv[n]);
                }
        int h_ = (colBase + wC * 64) >> 6;
        int s0g = rowBase + wR * 64;
        int b_ = s0g >> 9, sb = s0g & 511;
#pragma unroll
        for (int p = 0; p < 8; ++p) {
            int dd = p * 8 + (l >> 3), ch = l & 7;
            bf16x8 v = *reinterpret_cast<const bf16x8*>(ep + dd * 64 + ((ch ^ (dd & 7)) << 3));
            *reinterpret_cast<bf16x8*>(vT_out + (((size_t)(b_ * 8 + h_) * 64 + dd) << 9) + sb + ch * 8) = v;
        }
    }
}

// ---------------- W_eff = Wo + W1 @ Wo (bf16 out, fp32 resid from d_in) ----------------
// grid (4,4): C[j,k] = sum_m W1[j,m]*WoT[k,m] + Wo[j,k]
__global__ __launch_bounds__(256) void gemm_weff(const __hip_bfloat16* __restrict__ W1b,
                                                 const __hip_bfloat16* __restrict__ WoT,
                                                 const float* __restrict__ Wof,
                                                 __hip_bfloat16* __restrict__ weff) {
    __shared__ short lds[16384];
    int tid = threadIdx.x;
    int w = tid >> 6, l = tid & 63, lr = l & 15, lg = l >> 4;
    int wR = w >> 1, wC = w & 1;
    int rowBase = blockIdx.x * 128;
    int colBase = blockIdx.y * 128;

    f32x4 acc[4][4];
#pragma unroll
    for (int m = 0; m < 4; ++m)
#pragma unroll
        for (int n = 0; n < 4; ++n) acc[m][n] = (f32x4){0.f, 0.f, 0.f, 0.f};

    gemm_mainloop(W1b, WoT, rowBase, colBase, 16, lds, acc);

#pragma unroll
    for (int n = 0; n < 4; ++n) {
        int col = colBase + wC * 64 + n * 16 + lr;
#pragma unroll
        for (int m = 0; m < 4; ++m)
#pragma unroll
            for (int i = 0; i < 4; ++i) {
                int row = rowBase + wR * 64 + m * 16 + lg * 4 + i;
                size_t idx = (size_t)row * 512 + col;
                weff[idx] = __float2bfloat16(acc[m][n][i] + Wof[idx]);
            }
    }
}

// ---------------- final GEMM: out = ao @ W_eff^T + b_eff (fp32) ----------------
__global__ __launch_bounds__(256) void gemm_final(const __hip_bfloat16* __restrict__ A,
                                                  const __hip_bfloat16* __restrict__ W,
                                                  const float* __restrict__ bias,
                                                  float* __restrict__ outf) {
    __shared__ short lds[16384];
    int tid = threadIdx.x;
    int w = tid >> 6, l = tid & 63, lr = l & 15, lg = l >> 4;
    int wR = w >> 1, wC = w & 1;
    int rowBase = blockIdx.x * 128;
    int colBase = blockIdx.y * 128;

    f32x4 acc[4][4];
#pragma unroll
    for (int m = 0; m < 4; ++m)
#pragma unroll
        for (int n = 0; n < 4; ++n) acc[m][n] = (f32x4){0.f, 0.f, 0.f, 0.f};

    gemm_mainloop(A, W, rowBase, colBase, 16, lds, acc);

#pragma unroll
    for (int n = 0; n < 4; ++n) {
        int col = colBase + wC * 64 + n * 16 + lr;
        float bs = bias[col];
#pragma unroll
        for (int m = 0; m < 4; ++m)
#pragma unroll
            for (int i = 0; i < 4; ++i) {
                int row = rowBase + wR * 64 + m * 16 + lg * 4 + i;
                outf[(size_t)row * 512 + col] = acc[m][n][i] + bs;
            }
    }
}

// ---------------- flash attention + fused memV ----------------
// grid 1024: bh = blk & 127, qt = blk >> 7. out = (1-lam)*softmax(QK^T)@V + lam*(mem@V).
// mem@V reuses the staged V fragments; mem fragments loaded direct from global
// (prefetched at tile start; mem's masked entries are exact zeros).
__global__ __launch_bounds__(256, 2) void attn3_kernel(const __hip_bfloat16* __restrict__ Q,
                                                       const __hip_bfloat16* __restrict__ Km,
                                                       const __hip_bfloat16* __restrict__ VT,
                                                       const __hip_bfloat16* __restrict__ mem,
                                                       const float* __restrict__ l1,
                                                       __hip_bfloat16* __restrict__ outb) {
    __shared__ short lds[20480];          // K dbuf 8192 | V dbuf 8192 | P 4x1024 = 40KB
    short* Kb = lds;
    short* Vb = lds + 8192;
    int tid = threadIdx.x;
    int w = tid >> 6, l = tid & 63;
    int lr = l & 15, lg = l >> 4;
    int blk = blockIdx.x;
    int bh = blk & 127, qt = blk >> 7;
    int b = bh >> 3, h = bh & 7;
    int q0 = qt * 64;
    int nt = qt + 1;
    short* Pw = lds + 16384 + w * 1024;

    const char* Kg = (const char*)Km + (size_t)bh * 65536;
    const char* Vg = (const char*)VT + (size_t)bh * 65536;

    int o0 = w * 64 + l;
    const __hip_bfloat16* qp = Q + ((size_t)bh * 512 + q0 + w * 16 + lr) * 64 + lg * 8;
    bf16x8 qa0 = ldbf8(qp), qa1 = ldbf8(qp + 32);
    const __hip_bfloat16* memrow = mem + ((size_t)b * 512 + q0 + w * 16 + lr) * 512;
    float lam = l1[0];

    // stage tile 0
#pragma unroll
    for (int c = 0; c < 2; ++c) {
        int o = c * 256 + o0;
        int r = o >> 3, c16 = o & 7;
        int sw = ((c16 ^ (r & 7)) << 4);
        gload_lds16(Kg + r * 128 + sw, (char*)Kb + o * 16);
        gload_lds16(Vg + r * 1024 + sw, (char*)Vb + o * 16);
    }
    __syncthreads();

    f32x4 acc2[4], acc3[4];
#pragma unroll
    for (int n = 0; n < 4; ++n) {
        acc2[n] = (f32x4){0.f, 0.f, 0.f, 0.f};
        acc3[n] = (f32x4){0.f, 0.f, 0.f, 0.f};
    }
    float mrun[4] = {-3e38f, -3e38f, -3e38f, -3e38f};
    float psum[4] = {0.f, 0.f, 0.f, 0.f};

    for (int t = 0; t < nt; ++t) {
        // prefetch next K/V tile + this tile's mem fragments (consumed late)
        if (t + 1 < nt) {
#pragma unroll
            for (int c = 0; c < 2; ++c) {
                int o = c * 256 + o0;
                int r = o >> 3, c16 = o & 7;
                int sw = ((c16 ^ (r & 7)) << 4);
                gload_lds16(Kg + (t + 1) * 8192 + r * 128 + sw,
                            (char*)Kb + ((t + 1) & 1) * 8192 + o * 16);
                gload_lds16(Vg + r * 1024 + (t + 1) * 128 + sw,
                            (char*)Vb + ((t + 1) & 1) * 8192 + o * 16);
            }
        }
        bf16x8 ma0 = ldbf8(memrow + t * 64 + lg * 8);
        bf16x8 ma1 = ldbf8(memrow + t * 64 + 32 + lg * 8);
        const short* kb = Kb + (t & 1) * 4096;
        const short* vb = Vb + (t & 1) * 4096;

        f32x4 s4[4];
#pragma unroll
        for (int j = 0; j < 4; ++j) {
            int row = j * 16 + lr;
            int sw = row & 7;
            bf16x8 k0 = *reinterpret_cast<const bf16x8*>(kb + row * 64 + ((lg ^ sw) << 3));
            bf16x8 k1 = *reinterpret_cast<const bf16x8*>(kb + row * 64 + (((4 + lg) ^ sw) << 3));
            f32x4 cc = {0.f, 0.f, 0.f, 0.f};
            cc = __builtin_amdgcn_mfma_f32_16x16x32_bf16(qa0, k0, cc, 0, 0, 0);
            cc = __builtin_amdgcn_mfma_f32_16x16x32_bf16(qa1, k1, cc, 0, 0, 0);
            s4[j] = cc;
        }

        if (t == nt - 1) {
#pragma unroll
            for (int j = 0; j < 4; ++j) {
                int col = t * 64 + j * 16 + lr;
#pragma unroll
                for (int i = 0; i < 4; ++i) {
                    int rowg = q0 + w * 16 + lg * 4 + i;
                    s4[j][i] = (col <= rowg) ? s4[j][i] * 0.125f : -3e38f;
                }
            }
        } else {
#pragma unroll
            for (int j = 0; j < 4; ++j)
#pragma unroll
                for (int i = 0; i < 4; ++i) s4[j][i] *= 0.125f;
        }

        float tmax[4];
#pragma unroll
        for (int i = 0; i < 4; ++i)
            tmax[i] = fmaxf(fmaxf(s4[0][i], s4[1][i]), fmaxf(s4[2][i], s4[3][i]));
#pragma unroll
        for (int off = 1; off < 16; off <<= 1)
#pragma unroll
            for (int i = 0; i < 4; ++i) tmax[i] = fmaxf(tmax[i], __shfl_xor(tmax[i], off));

        float e[4][4];
#pragma unroll
        for (int i = 0; i < 4; ++i) {
            float mnew = fmaxf(mrun[i], tmax[i]);
            float sc = __expf(mrun[i] - mnew);
            mrun[i] = mnew;
            float ps = 0.f;
#pragma unroll
            for (int j = 0; j < 4; ++j) {
                float ee = __expf(s4[j][i] - mnew);
                e[j][i] = ee;
                ps += ee;
            }
            psum[i] = psum[i] * sc + ps;
#pragma unroll
            for (int n = 0; n < 4; ++n) acc2[n][i] *= sc;
        }

#pragma unroll
        for (int j = 0; j < 4; ++j)
#pragma unroll
            for (int i = 0; i < 4; ++i) {
                int rr = lg * 4 + i;
                int cc = j * 16 + lr;
                Pw[rr * 64 + (cc ^ ((rr & 7) << 3))] = (short)bfbits(e[j][i]);
            }

        // PV + memV MFMA (shared V fragments)
#pragma unroll
        for (int ksub = 0; ksub < 2; ++ksub) {
            bf16x8 pa = *reinterpret_cast<const bf16x8*>(
                Pw + lr * 64 + (((ksub * 4 + lg) ^ (lr & 7)) << 3));
            bf16x8 mfrag = (ksub == 0) ? ma0 : ma1;
#pragma unroll
            for (int n = 0; n < 4; ++n) {
                int d = n * 16 + lr;
                bf16x8 vf = *reinterpret_cast<const bf16x8*>(
                    vb + d * 64 + (((ksub * 4 + lg) ^ (d & 7)) << 3));
                acc2[n] = __builtin_amdgcn_mfma_f32_16x16x32_bf16(pa, vf, acc2[n], 0, 0, 0);
                acc3[n] = __builtin_amdgcn_mfma_f32_16x16x32_bf16(mfrag, vf, acc3[n], 0, 0, 0);
            }
        }
        __syncthreads();
    }

#pragma unroll
    for (int off = 1; off < 16; off <<= 1)
#pragma unroll
        for (int i = 0; i < 4; ++i) psum[i] += __shfl_xor(psum[i], off);
    float rinv[4];
#pragma unroll
    for (int i = 0; i < 4; ++i) rinv[i] = (1.0f - lam) / psum[i];

    __hip_bfloat16* op = outb + ((size_t)b * 512 + q0 + w * 16 + lg * 4) * 512 + h * 64;
#pragma unroll
    for (int n = 0; n < 4; ++n)
#pragma unroll
        for (int i = 0; i < 4; ++i)
            op[(size_t)i * 512 + n * 16 + lr] =
                __float2bfloat16(acc2[n][i] * rinv[i] + lam * acc3[n][i]);
}

// ---------------- LayerNorm (in-place on d_out) ----------------
__global__ __launch_bounds__(256) void ln_kernel(float* __restrict__ io,
                                                 const float* __restrict__ g,
                                                 const float* __restrict__ bb) {
    int tid = threadIdx.x;
    int w = tid >> 6, l = tid & 63;
    size_t row = (size_t)blockIdx.x * 4 + w;
    float* p = io + row * 512 + l * 8;
    float4 x0 = *reinterpret_cast<float4*>(p);
    float4 x1 = *reinterpret_cast<float4*>(p + 4);
    float xs[8] = {x0.x, x0.y, x0.z, x0.w, x1.x, x1.y, x1.z, x1.w};
    float s = 0.f;
#pragma unroll
    for (int j = 0; j < 8; ++j) s += xs[j];
#pragma unroll
    for (int off = 32; off >= 1; off >>= 1) s += __shfl_xor(s, off);
    float mu = s * (1.0f / 512.0f);
    float vs = 0.f;
#pragma unroll
    for (int j = 0; j < 8; ++j) { float d = xs[j] - mu; vs += d * d; }
#pragma unroll
    for (int off = 32; off >= 1; off >>= 1) vs += __shfl_xor(vs, off);
    float rstd = rsqrtf(vs * (1.0f / 512.0f) + 1e-5f);
    const float4 g0 = *reinterpret_cast<const float4*>(g + l * 8);
    const float4 g1 = *reinterpret_cast<const float4*>(g + l * 8 + 4);
    const float4 b0 = *reinterpret_cast<const float4*>(bb + l * 8);
    const float4 b1 = *reinterpret_cast<const float4*>(bb + l * 8 + 4);
    float gs[8] = {g0.x, g0.y, g0.z, g0.w, g1.x, g1.y, g1.z, g1.w};
    float bs[8] = {b0.x, b0.y, b0.z, b0.w, b1.x, b1.y, b1.z, b1.w};
    float ys[8];
#pragma unroll
    for (int j = 0; j < 8; ++j) ys[j] = (xs[j] - mu) * rstd * gs[j] + bs[j];
    float4 y0 = make_float4(ys[0], ys[1], ys[2], ys[3]);
    float4 y1 = make_float4(ys[4], ys[5], ys[6], ys[7]);
    *reinterpret_cast<float4*>(p) = y0;
    *reinterpret_cast<float4*>(p + 4) = y1;
}

// ---------------- host ----------------
extern "C" void kernel_launch(void* const* d_in, const int* in_sizes, int n_in,
                              void* d_out, int out_size, void* d_ws, size_t ws_size,
                              hipStream_t stream) {
    const float* inputs = (const float*)d_in[1];
    const float* ren    = (const float*)d_in[2];
    const float* ts     = (const float*)d_in[3];
    const float* Wq = (const float*)d_in[5];
    const float* bq = (const float*)d_in[6];
    const float* Wk = (const float*)d_in[7];
    const float* bk = (const float*)d_in[8];
    const float* Wv = (const float*)d_in[9];
    const float* bv = (const float*)d_in[10];
    const float* Wo = (const float*)d_in[11];
    const float* bo = (const float*)d_in[12];
    const float* W1 = (const float*)d_in[13];
    const float* b1 = (const float*)d_in[14];
    const float* ln_g = (const float*)d_in[15];
    const float* ln_b = (const float*)d_in[16];
    const float* l1   = (const float*)d_in[17];
    float* out = (float*)d_out;

    // ws layout:
    //   [0, 8M)                  in_bf -> reused as ao_bf after projections
    //   [8388608, +4*512K)       [Wq|Wk|Wv|W1] bf16
    //   [10485760, +512K)        WoT bf16
    //   [11010048, +512K)        W_eff bf16
    //   [11534336, +4K)          b_eff fp32
    //   [11538432, +8M)          q_bf
    //   [19927040, +8M)          k_bf
    //   [28315648, +8M)          vT_bf
    //   [36704256, +33.5M)       mem_bf           (total ~70 MB)
    char* ws = (char*)d_ws;
    __hip_bfloat16* in_bf  = (__hip_bfloat16*)(ws + 0);
    __hip_bfloat16* ao_bf  = (__hip_bfloat16*)(ws + 0);
    __hip_bfloat16* wq_bf  = (__hip_bfloat16*)(ws + 8388608);
    __hip_bfloat16* w1_bf  = (__hip_bfloat16*)(ws + 8388608 + 3 * 524288);
    __hip_bfloat16* woT_bf = (__hip_bfloat16*)(ws + 10485760);
    __hip_bfloat16* weff_bf= (__hip_bfloat16*)(ws + 11010048);
    float*          beff_f = (float*)(ws + 11534336);
    __hip_bfloat16* q_bf   = (__hip_bfloat16*)(ws + 11538432);
    __hip_bfloat16* k_bf   = (__hip_bfloat16*)(ws + 19927040);
    __hip_bfloat16* vT_bf  = (__hip_bfloat16*)(ws + 28315648);
    __hip_bfloat16* mem_bf = (__hip_bfloat16*)(ws + 36704256);

    // 1) conversions + W_eff/b_eff prep
    cvt_kernel<<<4096, 256, 0, stream>>>(inputs, in_bf, BS * D / 4);
    wcvt4_kernel<<<1024, 256, 0, stream>>>(Wq, Wk, Wv, W1, wq_bf);
    wtr_kernel<<<64, 256, 0, stream>>>(Wo, woT_bf);
    bprep_kernel<<<2, 256, 0, stream>>>(W1, bo, b1, beff_f);
    gemm_weff<<<dim3(4, 4), 256, 0, stream>>>(w1_bf, woT_bf, Wo, weff_bf);

    // 2) merged q/k/v projections (staged)
    gemm_qkv_s<<<dim3(64, 12), 256, 0, stream>>>(in_bf, wq_bf, bq, bk, bv, q_bf, k_bf, vT_bf);

    // 3) memory attention (head-independent, bf16, exact zeros in masked region)
    mem_attn_kernel<<<BS / 4, 256, 0, stream>>>(ren, ts, mem_bf);

    // 4) flash attention with fused memV: (1-lam)*softmax(QK^T)@V + lam*(mem@V)
    attn3_kernel<<<1024, 256, 0, stream>>>(q_bf, k_bf, vT_bf, mem_bf, l1, ao_bf);

    // 5) fused output+FFN GEMM: out = ao @ W_eff^T + b_eff  (fp32)
    gemm_final<<<dim3(64, 4), 256, 0, stream>>>(ao_bf, weff_bf, beff_f, out);

    // 6) LayerNorm in-place on d_out
    ln_kernel<<<BS / 4, 256, 0, stream>>>(out, ln_g, ln_b);
}

// Round 12
// 242.219 us; speedup vs baseline: 1.5674x; 1.0477x over previous
//
#include <hip/hip_runtime.h>
#include <hip/hip_bf16.h>

// Problem constants (fixed shapes)
constexpr int B = 16, S = 512, D = 512, H = 8, HD = 64;
constexpr int BS = B * S;   // 8192 rows

typedef __attribute__((ext_vector_type(8))) short bf16x8;
typedef __attribute__((ext_vector_type(4))) float f32x4;

#define DEVI __device__ __forceinline__

DEVI bf16x8 ldbf8(const __hip_bfloat16* p) {
    return *reinterpret_cast<const bf16x8*>(p);
}

DEVI unsigned short bfbits(float f) {
    __hip_bfloat16 h = __float2bfloat16(f);
    return __builtin_bit_cast(unsigned short, h);
}

DEVI void gload_lds16(const void* g, void* l) {
    __builtin_amdgcn_global_load_lds((const __attribute__((address_space(1))) void*)g,
                                     (__attribute__((address_space(3))) void*)l, 16, 0, 0);
}

// ---------------- fp32 -> bf16 conversion (vectorized) ----------------
__global__ __launch_bounds__(256) void cvt_kernel(const float* __restrict__ src,
                                                  __hip_bfloat16* __restrict__ dst,
                                                  int n4) {
    int i = blockIdx.x * 256 + threadIdx.x;
    if (i >= n4) return;
    float4 v = reinterpret_cast<const float4*>(src)[i];
    unsigned int lo = (unsigned int)bfbits(v.x) | ((unsigned int)bfbits(v.y) << 16);
    unsigned int hi = (unsigned int)bfbits(v.z) | ((unsigned int)bfbits(v.w) << 16);
    uint2 o; o.x = lo; o.y = hi;
    reinterpret_cast<uint2*>(dst)[i] = o;
}

// 4 weight matrices [Wq|Wk|Wv|W1] -> contiguous bf16 region.
__global__ __launch_bounds__(256) void wcvt4_kernel(const float* __restrict__ s0,
                                                    const float* __restrict__ s1,
                                                    const float* __restrict__ s2,
                                                    const float* __restrict__ s3,
                                                    __hip_bfloat16* __restrict__ dst) {
    int idx = blockIdx.x * 256 + threadIdx.x;      // [0, 4*65536)
    int wsel = idx >> 16;                          // uniform per block
    int off = idx & 65535;
    const float* s;
    switch (wsel) {
        case 0: s = s0; break;
        case 1: s = s1; break;
        case 2: s = s2; break;
        default: s = s3; break;
    }
    float4 v = reinterpret_cast<const float4*>(s)[off];
    unsigned int lo = (unsigned int)bfbits(v.x) | ((unsigned int)bfbits(v.y) << 16);
    unsigned int hi = (unsigned int)bfbits(v.z) | ((unsigned int)bfbits(v.w) << 16);
    uint2 o; o.x = lo; o.y = hi;
    reinterpret_cast<uint2*>(dst)[idx] = o;
}

// Transpose-convert: WoT[k][m] = bf16(Wo[m][k]). grid 64 (8x8 64-tiles), block 256.
__global__ __launch_bounds__(256) void wtr_kernel(const float* __restrict__ Wo,
                                                  __hip_bfloat16* __restrict__ WoT) {
    __shared__ float t64[64][65];
    int bx = blockIdx.x & 7, by = blockIdx.x >> 3;   // k-tile, m-tile
    int tc = threadIdx.x & 63, tr = threadIdx.x >> 6;
#pragma unroll
    for (int i = 0; i < 16; ++i) {
        int row = tr * 16 + i;
        t64[row][tc] = Wo[(size_t)(by * 64 + row) * 512 + bx * 64 + tc];
    }
    __syncthreads();
#pragma unroll
    for (int i = 0; i < 16; ++i) {
        int row = tr * 16 + i;    // k within tile
        WoT[(size_t)(bx * 64 + row) * 512 + by * 64 + tc] = __float2bfloat16(t64[tc][row]);
    }
}

// b_eff[j] = bo[j] + sum_m W1[j,m]*bo[m] + b1[j]. grid 2, block 256.
__global__ __launch_bounds__(256) void bprep_kernel(const float* __restrict__ W1,
                                                    const float* __restrict__ bo,
                                                    const float* __restrict__ b1,
                                                    float* __restrict__ beff) {
    int j = blockIdx.x * 256 + threadIdx.x;
    float s = 0.f;
    const float4* wr = reinterpret_cast<const float4*>(W1 + (size_t)j * 512);
    const float4* br = reinterpret_cast<const float4*>(bo);
    for (int m = 0; m < 128; ++m) {
        float4 a = wr[m], b = br[m];
        s += a.x * b.x + a.y * b.y + a.z * b.z + a.w * b.w;
    }
    beff[j] = bo[j] + s + b1[j];
}

// ---------------- mem_attn: softmax over log10(ren+1)+exp(-|ts|), causal ----------------
__global__ __launch_bounds__(256) void mem_attn_kernel(const float* __restrict__ ren,
                                                       const float* __restrict__ ts,
                                                       __hip_bfloat16* __restrict__ mem) {
    int tid = threadIdx.x;
    int w = tid >> 6, l = tid & 63;
    int row = blockIdx.x * 4 + w;        // b*S + q
    int qr = row & (S - 1);
    size_t base = (size_t)row * S + l * 8;
    float f[8];
    bool active = (l * 8 <= qr);
    if (active) {
        float4 r0 = *reinterpret_cast<const float4*>(ren + base);
        float4 r1 = *reinterpret_cast<const float4*>(ren + base + 4);
        float4 t0 = *reinterpret_cast<const float4*>(ts + base);
        float4 t1 = *reinterpret_cast<const float4*>(ts + base + 4);
        float rv[8] = {r0.x, r0.y, r0.z, r0.w, r1.x, r1.y, r1.z, r1.w};
        float tv[8] = {t0.x, t0.y, t0.z, t0.w, t1.x, t1.y, t1.z, t1.w};
#pragma unroll
        for (int j = 0; j < 8; ++j) {
            int c = l * 8 + j;
            f[j] = (c <= qr) ? (__log2f(rv[j] + 1.0f) * 0.3010299957f + __expf(-fabsf(tv[j])))
                             : -3.0e38f;
        }
    } else {
#pragma unroll
        for (int j = 0; j < 8; ++j) f[j] = -3.0e38f;
    }
    float m = -3.0e38f;
#pragma unroll
    for (int j = 0; j < 8; ++j) m = fmaxf(m, f[j]);
#pragma unroll
    for (int off = 32; off >= 1; off >>= 1) m = fmaxf(m, __shfl_xor(m, off));
    float s = 0.f;
#pragma unroll
    for (int j = 0; j < 8; ++j) { float e = __expf(f[j] - m); f[j] = e; s += e; }
#pragma unroll
    for (int off = 32; off >= 1; off >>= 1) s += __shfl_xor(s, off);
    float inv = 1.0f / s;
    bf16x8 o;
#pragma unroll
    for (int j = 0; j < 8; ++j) o[j] = (short)bfbits(f[j] * inv);
    *reinterpret_cast<bf16x8*>(mem + base) = o;
}

// ================= staged GEMM machinery =================
// Block tile 128x128, K-step 32, 4 waves 2x2. 3 LDS buffers (48 KB), prefetch
// distance 2, counted s_waitcnt vmcnt(4) so the next prefetch stays in flight
// across the barrier (T4 pattern) -- only tile t+1 is drained per iteration.
DEVI void stage_tiles(const __hip_bfloat16* __restrict__ A,
                      const __hip_bfloat16* __restrict__ W,
                      int rowBase, int colBase, int kt, short* ldsbuf, int tid) {
#pragma unroll
    for (int c = 0; c < 2; ++c) {
        int o = c * 256 + tid;
        int row = o & 127, ch = o >> 7;
        gload_lds16(A + (size_t)(rowBase + row) * 512 + kt * 32 + ch * 8,
                    (char*)ldsbuf + o * 16);
        gload_lds16(W + (size_t)(colBase + row) * 512 + kt * 32 + ch * 8,
                    (char*)ldsbuf + 8192 + o * 16);
    }
}

// ktiles must be >= 2 and uniform across the block (it is: 16 for all users).
DEVI void gemm_mainloop(const __hip_bfloat16* __restrict__ A,
                        const __hip_bfloat16* __restrict__ W,
                        int rowBase, int colBase, int ktiles,
                        short* lds, f32x4 (&acc)[4][4]) {
    int tid = threadIdx.x;
    int w = tid >> 6, l = tid & 63, lr = l & 15, lg = l >> 4;
    int wR = w >> 1, wC = w & 1;
    // prologue: stage tiles 0 and 1; wait for tile 0 (tile 1 stays in flight)
    stage_tiles(A, W, rowBase, colBase, 0, lds, tid);
    stage_tiles(A, W, rowBase, colBase, 1, lds + 8192, tid);
    asm volatile("s_waitcnt vmcnt(4)" ::: "memory");
    __builtin_amdgcn_s_barrier();
    __builtin_amdgcn_sched_barrier(0);
    int bufn = 2;   // next buffer to fill (rotates 0,1,2)
    int bufc = 0;   // current compute buffer
    for (int t = 0; t < ktiles; ++t) {
        if (t + 2 < ktiles) {
            stage_tiles(A, W, rowBase, colBase, t + 2, lds + bufn * 8192, tid);
            bufn = (bufn == 2) ? 0 : bufn + 1;
        }
        const short* ab = lds + bufc * 8192;
        bufc = (bufc == 2) ? 0 : bufc + 1;
        const short* bb = ab + 4096;
        bf16x8 af[4], bfr[4];
#pragma unroll
        for (int m = 0; m < 4; ++m)
            af[m] = *reinterpret_cast<const bf16x8*>(ab + (lg * 128 + wR * 64 + m * 16 + lr) * 8);
#pragma unroll
        for (int n = 0; n < 4; ++n)
            bfr[n] = *reinterpret_cast<const bf16x8*>(bb + (lg * 128 + wC * 64 + n * 16 + lr) * 8);
#pragma unroll
        for (int m = 0; m < 4; ++m)
#pragma unroll
            for (int n = 0; n < 4; ++n)
                acc[m][n] = __builtin_amdgcn_mfma_f32_16x16x32_bf16(af[m], bfr[n], acc[m][n], 0, 0, 0);
        // drain tile t+1 only; tile t+2's 4 loads stay in flight across barrier
        if (t + 2 < ktiles) {
            asm volatile("s_waitcnt vmcnt(4)" ::: "memory");
        } else {
            asm volatile("s_waitcnt vmcnt(0)" ::: "memory");
        }
        __builtin_amdgcn_s_barrier();
        __builtin_amdgcn_sched_barrier(0);
    }
}

// ---------------- merged q/k/v projection (staged) ----------------
__global__ __launch_bounds__(256) void gemm_qkv_s(const __hip_bfloat16* __restrict__ A,
                                                  const __hip_bfloat16* __restrict__ Wqkv,
                                                  const float* __restrict__ bq,
                                                  const float* __restrict__ bk,
                                                  const float* __restrict__ bv,
                                                  __hip_bfloat16* __restrict__ q_out,
                                                  __hip_bfloat16* __restrict__ k_out,
                                                  __hip_bfloat16* __restrict__ vT_out) {
    __shared__ short lds[24576];   // 48 KB: 3 pipeline bufs; reused for epilogue
    int tid = threadIdx.x;
    int w = tid >> 6, l = tid & 63, lr = l & 15, lg = l >> 4;
    int wR = w >> 1, wC = w & 1;
    int mat = blockIdx.y >> 2;
    int rowBase = blockIdx.x * 128;
    int colBase = (blockIdx.y & 3) * 128;
    const float* bias = (mat == 0) ? bq : (mat == 1) ? bk : bv;
    const __hip_bfloat16* W = Wqkv + (size_t)mat * 262144;

    f32x4 acc[4][4];
#pragma unroll
    for (int m = 0; m < 4; ++m)
#pragma unroll
        for (int n = 0; n < 4; ++n) acc[m][n] = (f32x4){0.f, 0.f, 0.f, 0.f};

    gemm_mainloop(A, W, rowBase, colBase, 16, lds, acc);
    short* ep = lds + w * 4096;    // 64x64 bf16 per wave
    float bsv[4];
#pragma unroll
    for (int n = 0; n < 4; ++n) bsv[n] = bias[colBase + wC * 64 + n * 16 + lr];

    if (mat < 2) {
        __hip_bfloat16* o = (mat == 0) ? q_out : k_out;
#pragma unroll
        for (int m = 0; m < 4; ++m)
#pragma unroll
            for (int n = 0; n < 4; ++n)
#pragma unroll
                for (int i = 0; i < 4; ++i) {
                    int rr = m * 16 + lg * 4 + i, cl = n * 16 + lr;
                    ep[rr * 64 + (cl ^ ((rr & 7) << 3))] = (short)bfbits(acc[m][n][i] + bsv[n]);
                }
        int h_ = (colBase + wC * 64) >> 6;
#pragma unroll
        for (int p = 0; p < 8; ++p) {
            int rr = p * 8 + (l >> 3), ch = l & 7;
            bf16x8 v = *reinterpret_cast<const bf16x8*>(ep + rr * 64 + ((ch ^ (rr & 7)) << 3));
            int grow = rowBase + wR * 64 + rr;
            int b_ = grow >> 9, s_ = grow & 511;
            *reinterpret_cast<bf16x8*>(o + (((size_t)(b_ * 8 + h_) * 512 + s_) << 6) + ch * 8) = v;
        }
    } else {
#pragma unroll
        for (int m = 0; m < 4; ++m)
#pragma unroll
            for (int n = 0; n < 4; ++n)
#pragma unroll
                for (int i = 0; i < 4; ++i) {
                    int ss = m * 16 + lg * 4 + i, dd = n * 16 + lr;
                    ep[dd * 64 + (ss ^ ((dd & 7) << 3))] = (short)bfbits(acc[m][n][i] + bsv[n]);
                }
        int h_ = (colBase + wC * 64) >> 6;
        int s0g = rowBase + wR * 64;
        int b_ = s0g >> 9, sb = s0g & 511;
#pragma unroll
        for (int p = 0; p < 8; ++p) {
            int dd = p * 8 + (l >> 3), ch = l & 7;
            bf16x8 v = *reinterpret_cast<const bf16x8*>(ep + dd * 64 + ((ch ^ (dd & 7)) << 3));
            *reinterpret_cast<bf16x8*>(vT_out + (((size_t)(b_ * 8 + h_) * 64 + dd) << 9) + sb + ch * 8) = v;
        }
    }
}

// ---------------- W_eff = Wo + W1 @ Wo (bf16 out, fp32 resid from d_in) ----------------
__global__ __launch_bounds__(256) void gemm_weff(const __hip_bfloat16* __restrict__ W1b,
                                                 const __hip_bfloat16* __restrict__ WoT,
                                                 const float* __restrict__ Wof,
                                                 __hip_bfloat16* __restrict__ weff) {
    __shared__ short lds[24576];
    int tid = threadIdx.x;
    int w = tid >> 6, l = tid & 63, lr = l & 15, lg = l >> 4;
    int wR = w >> 1, wC = w & 1;
    int rowBase = blockIdx.x * 128;
    int colBase = blockIdx.y * 128;

    f32x4 acc[4][4];
#pragma unroll
    for (int m = 0; m < 4; ++m)
#pragma unroll
        for (int n = 0; n < 4; ++n) acc[m][n] = (f32x4){0.f, 0.f, 0.f, 0.f};

    gemm_mainloop(W1b, WoT, rowBase, colBase, 16, lds, acc);

#pragma unroll
    for (int n = 0; n < 4; ++n) {
        int col = colBase + wC * 64 + n * 16 + lr;
#pragma unroll
        for (int m = 0; m < 4; ++m)
#pragma unroll
            for (int i = 0; i < 4; ++i) {
                int row = rowBase + wR * 64 + m * 16 + lg * 4 + i;
                size_t idx = (size_t)row * 512 + col;
                weff[idx] = __float2bfloat16(acc[m][n][i] + Wof[idx]);
            }
    }
}

// ---------------- final GEMM: out = ao @ W_eff^T + b_eff (fp32) ----------------
__global__ __launch_bounds__(256) void gemm_final(const __hip_bfloat16* __restrict__ A,
                                                  const __hip_bfloat16* __restrict__ W,
                                                  const float* __restrict__ bias,
                                                  float* __restrict__ outf) {
    __shared__ short lds[24576];
    int tid = threadIdx.x;
    int w = tid >> 6, l = tid & 63, lr = l & 15, lg = l >> 4;
    int wR = w >> 1, wC = w & 1;
    int rowBase = blockIdx.x * 128;
    int colBase = blockIdx.y * 128;

    f32x4 acc[4][4];
#pragma unroll
    for (int m = 0; m < 4; ++m)
#pragma unroll
        for (int n = 0; n < 4; ++n) acc[m][n] = (f32x4){0.f, 0.f, 0.f, 0.f};

    gemm_mainloop(A, W, rowBase, colBase, 16, lds, acc);

#pragma unroll
    for (int n = 0; n < 4; ++n) {
        int col = colBase + wC * 64 + n * 16 + lr;
        float bs = bias[col];
#pragma unroll
        for (int m = 0; m < 4; ++m)
#pragma unroll
            for (int i = 0; i < 4; ++i) {
                int row = rowBase + wR * 64 + m * 16 + lg * 4 + i;
                outf[(size_t)row * 512 + col] = acc[m][n][i] + bs;
            }
    }
}

// ---------------- flash attention + fused memV (verified r11) ----------------
__global__ __launch_bounds__(256, 2) void attn3_kernel(const __hip_bfloat16* __restrict__ Q,
                                                       const __hip_bfloat16* __restrict__ Km,
                                                       const __hip_bfloat16* __restrict__ VT,
                                                       const __hip_bfloat16* __restrict__ mem,
                                                       const float* __restrict__ l1,
                                                       __hip_bfloat16* __restrict__ outb) {
    __shared__ short lds[20480];          // K dbuf 8192 | V dbuf 8192 | P 4x1024 = 40KB
    short* Kb = lds;
    short* Vb = lds + 8192;
    int tid = threadIdx.x;
    int w = tid >> 6, l = tid & 63;
    int lr = l & 15, lg = l >> 4;
    int blk = blockIdx.x;
    int bh = blk & 127, qt = blk >> 7;
    int b = bh >> 3, h = bh & 7;
    int q0 = qt * 64;
    int nt = qt + 1;
    short* Pw = lds + 16384 + w * 1024;

    const char* Kg = (const char*)Km + (size_t)bh * 65536;
    const char* Vg = (const char*)VT + (size_t)bh * 65536;

    int o0 = w * 64 + l;
    const __hip_bfloat16* qp = Q + ((size_t)bh * 512 + q0 + w * 16 + lr) * 64 + lg * 8;
    bf16x8 qa0 = ldbf8(qp), qa1 = ldbf8(qp + 32);
    const __hip_bfloat16* memrow = mem + ((size_t)b * 512 + q0 + w * 16 + lr) * 512;
    float lam = l1[0];

    // stage tile 0
#pragma unroll
    for (int c = 0; c < 2; ++c) {
        int o = c * 256 + o0;
        int r = o >> 3, c16 = o & 7;
        int sw = ((c16 ^ (r & 7)) << 4);
        gload_lds16(Kg + r * 128 + sw, (char*)Kb + o * 16);
        gload_lds16(Vg + r * 1024 + sw, (char*)Vb + o * 16);
    }
    __syncthreads();

    f32x4 acc2[4], acc3[4];
#pragma unroll
    for (int n = 0; n < 4; ++n) {
        acc2[n] = (f32x4){0.f, 0.f, 0.f, 0.f};
        acc3[n] = (f32x4){0.f, 0.f, 0.f, 0.f};
    }
    float mrun[4] = {-3e38f, -3e38f, -3e38f, -3e38f};
    float psum[4] = {0.f, 0.f, 0.f, 0.f};

    for (int t = 0; t < nt; ++t) {
        // prefetch next K/V tile + this tile's mem fragments (consumed late)
        if (t + 1 < nt) {
#pragma unroll
            for (int c = 0; c < 2; ++c) {
                int o = c * 256 + o0;
                int r = o >> 3, c16 = o & 7;
                int sw = ((c16 ^ (r & 7)) << 4);
                gload_lds16(Kg + (t + 1) * 8192 + r * 128 + sw,
                            (char*)Kb + ((t + 1) & 1) * 8192 + o * 16);
                gload_lds16(Vg + r * 1024 + (t + 1) * 128 + sw,
                            (char*)Vb + ((t + 1) & 1) * 8192 + o * 16);
            }
        }
        bf16x8 ma0 = ldbf8(memrow + t * 64 + lg * 8);
        bf16x8 ma1 = ldbf8(memrow + t * 64 + 32 + lg * 8);
        const short* kb = Kb + (t & 1) * 4096;
        const short* vb = Vb + (t & 1) * 4096;

        f32x4 s4[4];
#pragma unroll
        for (int j = 0; j < 4; ++j) {
            int row = j * 16 + lr;
            int sw = row & 7;
            bf16x8 k0 = *reinterpret_cast<const bf16x8*>(kb + row * 64 + ((lg ^ sw) << 3));
            bf16x8 k1 = *reinterpret_cast<const bf16x8*>(kb + row * 64 + (((4 + lg) ^ sw) << 3));
            f32x4 cc = {0.f, 0.f, 0.f, 0.f};
            cc = __builtin_amdgcn_mfma_f32_16x16x32_bf16(qa0, k0, cc, 0, 0, 0);
            cc = __builtin_amdgcn_mfma_f32_16x16x32_bf16(qa1, k1, cc, 0, 0, 0);
            s4[j] = cc;
        }

        if (t == nt - 1) {
#pragma unroll
            for (int j = 0; j < 4; ++j) {
                int col = t * 64 + j * 16 + lr;
#pragma unroll
                for (int i = 0; i < 4; ++i) {
                    int rowg = q0 + w * 16 + lg * 4 + i;
                    s4[j][i] = (col <= rowg) ? s4[j][i] * 0.125f : -3e38f;
                }
            }
        } else {
#pragma unroll
            for (int j = 0; j < 4; ++j)
#pragma unroll
                for (int i = 0; i < 4; ++i) s4[j][i] *= 0.125f;
        }

        float tmax[4];
#pragma unroll
        for (int i = 0; i < 4; ++i)
            tmax[i] = fmaxf(fmaxf(s4[0][i], s4[1][i]), fmaxf(s4[2][i], s4[3][i]));
#pragma unroll
        for (int off = 1; off < 16; off <<= 1)
#pragma unroll
            for (int i = 0; i < 4; ++i) tmax[i] = fmaxf(tmax[i], __shfl_xor(tmax[i], off));

        float e[4][4];
#pragma unroll
        for (int i = 0; i < 4; ++i) {
            float mnew = fmaxf(mrun[i], tmax[i]);
            float sc = __expf(mrun[i] - mnew);
            mrun[i] = mnew;
            float ps = 0.f;
#pragma unroll
            for (int j = 0; j < 4; ++j) {
                float ee = __expf(s4[j][i] - mnew);
                e[j][i] = ee;
                ps += ee;
            }
            psum[i] = psum[i] * sc + ps;
#pragma unroll
            for (int n = 0; n < 4; ++n) acc2[n][i] *= sc;
        }

#pragma unroll
        for (int j = 0; j < 4; ++j)
#pragma unroll
            for (int i = 0; i < 4; ++i) {
                int rr = lg * 4 + i;
                int cc = j * 16 + lr;
                Pw[rr * 64 + (cc ^ ((rr & 7) << 3))] = (short)bfbits(e[j][i]);
            }

        // PV + memV MFMA (shared V fragments)
#pragma unroll
        for (int ksub = 0; ksub < 2; ++ksub) {
            bf16x8 pa = *reinterpret_cast<const bf16x8*>(
                Pw + lr * 64 + (((ksub * 4 + lg) ^ (lr & 7)) << 3));
            bf16x8 mfrag = (ksub == 0) ? ma0 : ma1;
#pragma unroll
            for (int n = 0; n < 4; ++n) {
                int d = n * 16 + lr;
                bf16x8 vf = *reinterpret_cast<const bf16x8*>(
                    vb + d * 64 + (((ksub * 4 + lg) ^ (d & 7)) << 3));
                acc2[n] = __builtin_amdgcn_mfma_f32_16x16x32_bf16(pa, vf, acc2[n], 0, 0, 0);
                acc3[n] = __builtin_amdgcn_mfma_f32_16x16x32_bf16(mfrag, vf, acc3[n], 0, 0, 0);
            }
        }
        __syncthreads();
    }

#pragma unroll
    for (int off = 1; off < 16; off <<= 1)
#pragma unroll
        for (int i = 0; i < 4; ++i) psum[i] += __shfl_xor(psum[i], off);
    float rinv[4];
#pragma unroll
    for (int i = 0; i < 4; ++i) rinv[i] = (1.0f - lam) / psum[i];

    __hip_bfloat16* op = outb + ((size_t)b * 512 + q0 + w * 16 + lg * 4) * 512 + h * 64;
#pragma unroll
    for (int n = 0; n < 4; ++n)
#pragma unroll
        for (int i = 0; i < 4; ++i)
            op[(size_t)i * 512 + n * 16 + lr] =
                __float2bfloat16(acc2[n][i] * rinv[i] + lam * acc3[n][i]);
}

// ---------------- LayerNorm (in-place on d_out) ----------------
__global__ __launch_bounds__(256) void ln_kernel(float* __restrict__ io,
                                                 const float* __restrict__ g,
                                                 const float* __restrict__ bb) {
    int tid = threadIdx.x;
    int w = tid >> 6, l = tid & 63;
    size_t row = (size_t)blockIdx.x * 4 + w;
    float* p = io + row * 512 + l * 8;
    float4 x0 = *reinterpret_cast<float4*>(p);
    float4 x1 = *reinterpret_cast<float4*>(p + 4);
    float xs[8] = {x0.x, x0.y, x0.z, x0.w, x1.x, x1.y, x1.z, x1.w};
    float s = 0.f;
#pragma unroll
    for (int j = 0; j < 8; ++j) s += xs[j];
#pragma unroll
    for (int off = 32; off >= 1; off >>= 1) s += __shfl_xor(s, off);
    float mu = s * (1.0f / 512.0f);
    float vs = 0.f;
#pragma unroll
    for (int j = 0; j < 8; ++j) { float d = xs[j] - mu; vs += d * d; }
#pragma unroll
    for (int off = 32; off >= 1; off >>= 1) vs += __shfl_xor(vs, off);
    float rstd = rsqrtf(vs * (1.0f / 512.0f) + 1e-5f);
    const float4 g0 = *reinterpret_cast<const float4*>(g + l * 8);
    const float4 g1 = *reinterpret_cast<const float4*>(g + l * 8 + 4);
    const float4 b0 = *reinterpret_cast<const float4*>(bb + l * 8);
    const float4 b1 = *reinterpret_cast<const float4*>(bb + l * 8 + 4);
    float gs[8] = {g0.x, g0.y, g0.z, g0.w, g1.x, g1.y, g1.z, g1.w};
    float bs[8] = {b0.x, b0.y, b0.z, b0.w, b1.x, b1.y, b1.z, b1.w};
    float ys[8];
#pragma unroll
    for (int j = 0; j < 8; ++j) ys[j] = (xs[j] - mu) * rstd * gs[j] + bs[j];
    float4 y0 = make_float4(ys[0], ys[1], ys[2], ys[3]);
    float4 y1 = make_float4(ys[4], ys[5], ys[6], ys[7]);
    *reinterpret_cast<float4*>(p) = y0;
    *reinterpret_cast<float4*>(p + 4) = y1;
}

// ---------------- host ----------------
extern "C" void kernel_launch(void* const* d_in, const int* in_sizes, int n_in,
                              void* d_out, int out_size, void* d_ws, size_t ws_size,
                              hipStream_t stream) {
    const float* inputs = (const float*)d_in[1];
    const float* ren    = (const float*)d_in[2];
    const float* ts     = (const float*)d_in[3];
    const float* Wq = (const float*)d_in[5];
    const float* bq = (const float*)d_in[6];
    const float* Wk = (const float*)d_in[7];
    const float* bk = (const float*)d_in[8];
    const float* Wv = (const float*)d_in[9];
    const float* bv = (const float*)d_in[10];
    const float* Wo = (const float*)d_in[11];
    const float* bo = (const float*)d_in[12];
    const float* W1 = (const float*)d_in[13];
    const float* b1 = (const float*)d_in[14];
    const float* ln_g = (const float*)d_in[15];
    const float* ln_b = (const float*)d_in[16];
    const float* l1   = (const float*)d_in[17];
    float* out = (float*)d_out;

    char* ws = (char*)d_ws;
    __hip_bfloat16* in_bf  = (__hip_bfloat16*)(ws + 0);
    __hip_bfloat16* ao_bf  = (__hip_bfloat16*)(ws + 0);
    __hip_bfloat16* wq_bf  = (__hip_bfloat16*)(ws + 8388608);
    __hip_bfloat16* w1_bf  = (__hip_bfloat16*)(ws + 8388608 + 3 * 524288);
    __hip_bfloat16* woT_bf = (__hip_bfloat16*)(ws + 10485760);
    __hip_bfloat16* weff_bf= (__hip_bfloat16*)(ws + 11010048);
    float*          beff_f = (float*)(ws + 11534336);
    __hip_bfloat16* q_bf   = (__hip_bfloat16*)(ws + 11538432);
    __hip_bfloat16* k_bf   = (__hip_bfloat16*)(ws + 19927040);
    __hip_bfloat16* vT_bf  = (__hip_bfloat16*)(ws + 28315648);
    __hip_bfloat16* mem_bf = (__hip_bfloat16*)(ws + 36704256);

    // 1) conversions + W_eff/b_eff prep
    cvt_kernel<<<4096, 256, 0, stream>>>(inputs, in_bf, BS * D / 4);
    wcvt4_kernel<<<1024, 256, 0, stream>>>(Wq, Wk, Wv, W1, wq_bf);
    wtr_kernel<<<64, 256, 0, stream>>>(Wo, woT_bf);
    bprep_kernel<<<2, 256, 0, stream>>>(W1, bo, b1, beff_f);
    gemm_weff<<<dim3(4, 4), 256, 0, stream>>>(w1_bf, woT_bf, Wo, weff_bf);

    // 2) merged q/k/v projections (3-buffer pipelined)
    gemm_qkv_s<<<dim3(64, 12), 256, 0, stream>>>(in_bf, wq_bf, bq, bk, bv, q_bf, k_bf, vT_bf);

    // 3) memory attention (head-independent, bf16, exact zeros in masked region)
    mem_attn_kernel<<<BS / 4, 256, 0, stream>>>(ren, ts, mem_bf);

    // 4) flash attention with fused memV: (1-lam)*softmax(QK^T)@V + lam*(mem@V)
    attn3_kernel<<<1024, 256, 0, stream>>>(q_bf, k_bf, vT_bf, mem_bf, l1, ao_bf);

    // 5) fused output+FFN GEMM: out = ao @ W_eff^T + b_eff  (fp32)
    gemm_final<<<dim3(64, 4), 256, 0, stream>>>(ao_bf, weff_bf, beff_f, out);

    // 6) LayerNorm in-place on d_out
    ln_kernel<<<BS / 4, 256, 0, stream>>>(out, ln_g, ln_b);
}